// Round 16
// baseline (593.266 us; speedup 1.0000x reference)
//
#include <hip/hip_runtime.h>
#include <stdint.h>

typedef __attribute__((ext_vector_type(4))) float f32x4;
typedef __attribute__((ext_vector_type(8))) __bf16 bf16x8;

#define DEVINL __device__ __forceinline__

// ---------------- sizes ----------------
constexpr int T_LEN = 1024;
constexpr int CDIM  = 2048;
constexpr int MROWS = 2048;               // B*T
constexpr size_t MC = (size_t)MROWS * CDIM;

// ---------------- ws offsets (bytes) ----------------
constexpr size_t SZ_BF  = MC * 2;
constexpr size_t SZ_F32 = MC * 4;
constexpr size_t oXr  = 0;
constexpr size_t oXw  = oXr + SZ_BF;
constexpr size_t oXk  = oXw + SZ_BF;
constexpr size_t oXv  = oXk + SZ_BF;
constexpr size_t oXa  = oXv + SZ_BF;
constexpr size_t oXg  = oXa + SZ_BF;
constexpr size_t oWr  = oXg + SZ_BF;
constexpr size_t oWk  = oWr + SZ_BF;
constexpr size_t oWv  = oWk + SZ_BF;
constexpr size_t oWo  = oWv + SZ_BF;
constexpr size_t oW1T = oWo + SZ_BF;          // [128][2048] bf16 (pad rows>=96 zero)
constexpr size_t oA1T = oW1T + 524288;
constexpr size_t oV1T = oA1T + 524288;        // [128][2048] (pad>=64 zero)
constexpr size_t oG1T = oV1T + 524288;        // [256][2048]
constexpr size_t oW2T = oG1T + 1048576;       // [2048][128] (pad cols>=96 zero)
constexpr size_t oA2T = oW2T + 524288;
constexpr size_t oV2T = oA2T + 524288;
constexpr size_t oG2T = oV2T + 524288;        // [2048][256]
constexpr size_t oHw  = oG2T + 1048576;       // [2048][128] bf16
constexpr size_t oHa  = oHw + 524288;
constexpr size_t oHv  = oHa + 524288;
constexpr size_t oHg  = oHv + 524288;         // [2048][256]
constexpr size_t oR   = oHg + 1048576;        // fp32 [M][C]
constexpr size_t oK   = oR  + SZ_F32;
constexpr size_t oV   = oK  + SZ_F32;
constexpr size_t oWW  = oV  + SZ_F32;
constexpr size_t oAA  = oWW + SZ_F32;
constexpr size_t oBB  = oAA + SZ_F32;
constexpr size_t oG   = oBB + SZ_F32;
constexpr size_t oO   = oG  + SZ_F32;
constexpr size_t oAout= oO  + SZ_F32;         // bf16 [M][C]

// ---------------- helpers ----------------
DEVINL unsigned short f2bf(float f) {
  uint32_t u = __builtin_bit_cast(uint32_t, f);
  u += 0x7fffu + ((u >> 16) & 1u);            // RNE
  return (unsigned short)(u >> 16);
}
DEVINL void st_bf4(unsigned short* p, f32x4 v) {
  ushort4 o;
  o.x = f2bf(v[0]); o.y = f2bf(v[1]); o.z = f2bf(v[2]); o.w = f2bf(v[3]);
  *(ushort4*)p = o;
}
DEVINL void gload16(const void* g, void* l) {
  __builtin_amdgcn_global_load_lds(
      (const __attribute__((address_space(1))) unsigned int*)g,
      (__attribute__((address_space(3))) unsigned int*)l, 16, 0, 0);
}

// ---- VALU-speed cross-lane reduce hops (register-only; no LDS pipe) ----
// Sum-reductions tolerate rotations: rot4+rot8 within a 16-lane row sums the
// 4 stride-4 partners (lane&3 class preserved, 16%4==0).
// NOTE (R15 lesson): DPP control MUST be a compile-time constant -> template.
template <int CTL>
DEVINL float redrot(float x) {               // CTL: 0x124=row_ror:4, 0x128=row_ror:8
  int y = __builtin_amdgcn_update_dpp(0, __builtin_bit_cast(int, x),
                                      CTL, 0xF, 0xF, true);
  return x + __builtin_bit_cast(float, y);
}
// xor16: v_permlane16_swap_b32 (HW-verified in R14)
#if __has_builtin(__builtin_amdgcn_permlane16_swap)
DEVINL float red16(float x, bool evenrow) {
  unsigned xi = __builtin_bit_cast(unsigned, x);
  auto r = __builtin_amdgcn_permlane16_swap(xi, xi, false, false);
  unsigned oth = evenrow ? (unsigned)r[1] : (unsigned)r[0];
  return x + __builtin_bit_cast(float, oth);
}
#else
DEVINL float red16(float x, bool) { return x + __shfl_xor(x, 16); }
#endif
// xor32: v_permlane32_swap_b32 (HW-verified in R14)
#if __has_builtin(__builtin_amdgcn_permlane32_swap)
DEVINL float red32(float x, bool lowhalf) {
  unsigned xi = __builtin_bit_cast(unsigned, x);
  auto r = __builtin_amdgcn_permlane32_swap(xi, xi, false, false);
  unsigned oth = lowhalf ? (unsigned)r[1] : (unsigned)r[0];
  return x + __builtin_bit_cast(float, oth);
}
#else
DEVINL float red32(float x, bool) { return x + __shfl_xor(x, 32); }
#endif

// ---------------- fp32 -> bf16 convert, 4 matrices per launch ----------------
// grid (4096, 4), n4 = 1048576 float4-chunks PER matrix (2048*2048/4).
struct Conv4 { const float* s0; const float* s1; const float* s2; const float* s3;
               unsigned short* d0; unsigned short* d1; unsigned short* d2; unsigned short* d3; };
__global__ void k_conv4(Conv4 c, int n4) {
  int i = blockIdx.x * 256 + threadIdx.x;
  if (i >= n4) return;
  const float* s = (blockIdx.y == 0) ? c.s0 : (blockIdx.y == 1) ? c.s1
                   : (blockIdx.y == 2) ? c.s2 : c.s3;
  unsigned short* d = (blockIdx.y == 0) ? c.d0 : (blockIdx.y == 1) ? c.d1
                      : (blockIdx.y == 2) ? c.d2 : c.d3;
  f32x4 v = *(const f32x4*)(s + (size_t)i * 4);
  st_bf4(d + (size_t)i * 4, v);
}

// ---------------- transpose + zero-pad, 8 jobs in one launch ----------------
struct TpJobs {
  const float* src[8];
  unsigned short* dst[8];
  int sR[8]; int sC[8]; int dR[8]; int dC[8];
};
__global__ void k_tp8(TpJobs jt) {
  const int j = blockIdx.y;
  const int n = jt.dR[j] * jt.dC[j];
  int i = blockIdx.x * 256 + threadIdx.x;
  if (i >= n) return;
  const int dC = jt.dC[j], sR = jt.sR[j], sC = jt.sC[j];
  int r = i / dC, c = i - r * dC;
  float v = (r < sC && c < sR) ? jt.src[j][(size_t)c * sC + r] : 0.f;
  jt.dst[j][i] = f2bf(v);
}

// ---------------- token shift + 6 mixes -> bf16 ----------------
__global__ void k_mix(const float* __restrict__ x, const float* __restrict__ shift,
                      const float* __restrict__ cr, const float* __restrict__ cw,
                      const float* __restrict__ ck, const float* __restrict__ cv,
                      const float* __restrict__ ca, const float* __restrict__ cg,
                      unsigned short* __restrict__ Xr, unsigned short* __restrict__ Xw,
                      unsigned short* __restrict__ Xk, unsigned short* __restrict__ Xv,
                      unsigned short* __restrict__ Xa, unsigned short* __restrict__ Xg) {
  int i = blockIdx.x * 256 + threadIdx.x;      // one float4 per thread
  size_t e = (size_t)i * 4;
  int m = (int)(e >> 11);
  int c = (int)(e & 2047);
  int t = m & (T_LEN - 1);
  int b = m >> 10;
  f32x4 xc = *(const f32x4*)(x + e);
  f32x4 pv = (t == 0) ? *(const f32x4*)(shift + (size_t)b * CDIM + c)
                      : *(const f32x4*)(x + e - CDIM);
  f32x4 xx = pv - xc;
  st_bf4(Xr + e, xc + xx * (*(const f32x4*)(cr + c)));
  st_bf4(Xw + e, xc + xx * (*(const f32x4*)(cw + c)));
  st_bf4(Xk + e, xc + xx * (*(const f32x4*)(ck + c)));
  st_bf4(Xv + e, xc + xx * (*(const f32x4*)(cv + c)));
  st_bf4(Xa + e, xc + xx * (*(const f32x4*)(ca + c)));
  st_bf4(Xg + e, xc + xx * (*(const f32x4*)(cg + c)));
}

// ---------------- NT bf16 GEMM: C[m][n] = sum_k A[m][k]*B[n][k] ----------------
// m97 structure: 128x128 tile, BK=32, linear [128][32] LDS, global_load_lds w=16,
// 2-barrier loop, 4 waves (2x2 of 64x64), mfma 16x16x32 bf16.
// Per-job ldc/n; blocks with colB >= n early-exit (lets jobs of different N batch).
struct GemmJob { const unsigned short* A; const unsigned short* B; void* C; int epi; int ldc; int n; };
struct GemmBatch { GemmJob j[4]; };

__global__ __launch_bounds__(256) void k_gemm_nt(GemmBatch gb, int K) {
  const GemmJob jb = gb.j[blockIdx.z];
  const int colB = blockIdx.x * 128;
  if (colB >= jb.n) return;
  const int ldc = jb.ldc;
  __shared__ __align__(16) unsigned short As[128 * 32];
  __shared__ __align__(16) unsigned short Bs[128 * 32];
  const int tid  = threadIdx.x;
  const int lane = tid & 63;
  const int wv   = tid >> 6;
  const int wm = wv >> 1, wn = wv & 1;
  const int rowB = blockIdx.y * 128;
  // staging: 8 chunks of 1KB (16 rows x 64B); wave wv owns chunks wv and wv+4
  const size_t rsb = (size_t)K * 2;           // row stride bytes
  const int c0 = wv, c1 = wv + 4;
  const char* Ag0 = (const char*)jb.A + (size_t)(rowB + c0 * 16 + (lane >> 2)) * rsb + (lane & 3) * 16;
  const char* Ag1 = (const char*)jb.A + (size_t)(rowB + c1 * 16 + (lane >> 2)) * rsb + (lane & 3) * 16;
  const char* Bg0 = (const char*)jb.B + (size_t)(colB + c0 * 16 + (lane >> 2)) * rsb + (lane & 3) * 16;
  const char* Bg1 = (const char*)jb.B + (size_t)(colB + c1 * 16 + (lane >> 2)) * rsb + (lane & 3) * 16;
  unsigned short* Al0 = As + c0 * 512;        // wave-uniform LDS base
  unsigned short* Al1 = As + c1 * 512;
  unsigned short* Bl0 = Bs + c0 * 512;
  unsigned short* Bl1 = Bs + c1 * 512;
  f32x4 acc[4][4];
#pragma unroll
  for (int mi = 0; mi < 4; ++mi)
#pragma unroll
    for (int ni = 0; ni < 4; ++ni) acc[mi][ni] = (f32x4){0.f, 0.f, 0.f, 0.f};
  const int KT = K >> 5;
  const int fr = lane & 15, fk = (lane >> 4) * 8;
  for (int kt = 0; kt < KT; ++kt) {
    __syncthreads();                          // prior-iter LDS reads complete
    gload16(Ag0, Al0); gload16(Ag1, Al1);
    gload16(Bg0, Bl0); gload16(Bg1, Bl1);
    Ag0 += 64; Ag1 += 64; Bg0 += 64; Bg1 += 64;
    __syncthreads();                          // drains vmcnt -> LDS tile ready
    bf16x8 af[4], bfv[4];
#pragma unroll
    for (int mi = 0; mi < 4; ++mi)
      af[mi] = *(const bf16x8*)&As[(wm * 64 + mi * 16 + fr) * 32 + fk];
#pragma unroll
    for (int ni = 0; ni < 4; ++ni)
      bfv[ni] = *(const bf16x8*)&Bs[(wn * 64 + ni * 16 + fr) * 32 + fk];
#pragma unroll
    for (int mi = 0; mi < 4; ++mi)
#pragma unroll
      for (int ni = 0; ni < 4; ++ni)
        acc[mi][ni] = __builtin_amdgcn_mfma_f32_16x16x32_bf16(af[mi], bfv[ni], acc[mi][ni], 0, 0, 0);
  }
  // epilogue: C/D layout col=lane&15, row=(lane>>4)*4+j
  const int er = (lane >> 4) * 4, ec = lane & 15;
  if (jb.epi == 0) {
    float* Cf = (float*)jb.C;
#pragma unroll
    for (int mi = 0; mi < 4; ++mi)
#pragma unroll
      for (int ni = 0; ni < 4; ++ni) {
        int row0 = rowB + wm * 64 + mi * 16 + er;
        int col  = colB + wn * 64 + ni * 16 + ec;
#pragma unroll
        for (int j = 0; j < 4; ++j)
          Cf[(size_t)(row0 + j) * ldc + col] = acc[mi][ni][j];
      }
  } else {
    unsigned short* Cb = (unsigned short*)jb.C;
#pragma unroll
    for (int mi = 0; mi < 4; ++mi)
#pragma unroll
      for (int ni = 0; ni < 4; ++ni) {
        int row0 = rowB + wm * 64 + mi * 16 + er;
        int col  = colB + wn * 64 + ni * 16 + ec;
#pragma unroll
        for (int j = 0; j < 4; ++j) {
          float val = acc[mi][ni][j];
          if (jb.epi == 2) val = tanhf(val);
          else if (jb.epi == 3) val = 1.f / (1.f + __expf(-val));
          Cb[(size_t)(row0 + j) * ldc + col] = f2bf(val);
        }
      }
  }
}

// ---------------- post-GEMM elementwise + per-head kk normalize ----------------
__global__ __launch_bounds__(256) void k_post(
    float* __restrict__ Kb, float* __restrict__ Vb, float* __restrict__ Wb,
    float* __restrict__ Ab, float* __restrict__ Bb,
    const float* __restrict__ vf, const float* __restrict__ w0,
    const float* __restrict__ a0, const float* __restrict__ v0,
    const float* __restrict__ kkc, const float* __restrict__ kac) {
  int gw = blockIdx.x * 4 + (threadIdx.x >> 6);
  int lane = threadIdx.x & 63;
  int m = gw >> 5, h = gw & 31;
  int c = h * 64 + lane;
  size_t idx = (size_t)m * CDIM + c;
  float kraw = Kb[idx], vraw = Vb[idx], wlr = Wb[idx], alr = Ab[idx], vlr = Bb[idx];
  float z = w0[c] + wlr;
  float sg = 1.f / (1.f + __expf(-z));
  float wdec = __expf(-0.60653065971f * sg);  // exp(-exp(-softplus(-z)-0.5))
  float a = 1.f / (1.f + __expf(-(a0[c] + alr)));
  float vgate = 1.f / (1.f + __expf(-(v0[c] + vlr)));
  float v = vraw + (vf[idx] - vraw) * vgate;
  float kk = kraw * kkc[c];
  float s2 = kk * kk;
#pragma unroll
  for (int off = 32; off; off >>= 1) s2 += __shfl_xor(s2, off);
  float inv = 1.f / fmaxf(sqrtf(s2), 1e-12f);
  kk *= inv;
  float kn = kraw * (1.f + (a - 1.f) * kac[c]);
  Wb[idx] = wdec; Vb[idx] = v; Kb[idx] = kn; Ab[idx] = -kk; Bb[idx] = kk * a;
}

// ---------------- RWKV-7 recurrence ----------------
// R14 skeleton (staging stream / ring algebra / G alternation / deferred-o /
// ping-pong prefetch: byte-identical) with 4-v-row lane geometry:
//   vr = lane&3 (4 v-rows/block), kq = lane>>2 (16 k-groups of 4)
//   1024 blocks (vo in 0..15) => 4 blocks/CU = 1 wave/SIMD (2x TLP).
// Per-lane work halves (s = one f32x4; 5 b128 + 1 b32 reads/slot).
// k-reduce over 16 stride-4 lanes: rot4 + rot8 (DPP row_ror, sum-invariant)
// + permlane16/32 swaps (HW-verified R14) -- all VALU.
__global__ __launch_bounds__(64) void k_scan(
    const float* __restrict__ Rb, const float* __restrict__ Wb,
    const float* __restrict__ Kb, const float* __restrict__ Vb,
    const float* __restrict__ Ab, const float* __restrict__ Bb,
    const float* __restrict__ S0, float* __restrict__ Ob,
    float* __restrict__ Sf) {
  const int bid = blockIdx.x;
  const int bh = bid & 63, vo = bid >> 6;     // vo in 0..15; stride 64 => same XCD
  const int b = bh >> 5, h = bh & 31;
  const int lane = threadIdx.x;
  const int vr = lane & 3;
  const int kq = lane >> 2;
  const int gv = vo * 4 + vr;                 // global v-row in head
  const int kk0 = kq * 4;                     // 4 k per lane
  const bool evr = ((lane >> 4) & 1) == 0;    // even 16-lane row
  const bool lhf = lane < 32;                 // lower 32-lane half
  __shared__ __align__(16) float stg[4][6][64];
  const size_t rowBase = (size_t)b * T_LEN * CDIM;
  const size_t colBase = (size_t)h * 64;
  const float* pR = Rb + rowBase + colBase + lane;
  const float* pW = Wb + rowBase + colBase + lane;
  const float* pK = Kb + rowBase + colBase + lane;
  const float* pV = Vb + rowBase + colBase + lane;
  const float* pA = Ab + rowBase + colBase + lane;
  const float* pB = Bb + rowBase + colBase + lane;
  float* Obp = Ob + rowBase + colBase + vo * 4 + lane;   // valid for lane<4
  f32x4 s0;
  {
    const float* sp = S0 + (((size_t)(b * 32 + h)) * 64 + gv) * 64 + kk0;
    s0 = *(const f32x4*)sp;
  }
  float gA[6], gB[6];
  {   // prologue: stg[0]<-t0, stg[1]<-t1, gA<-t2, gB<-t3   (R14-exact)
    float h0[6], h1[6];
    h0[0] = pR[0]; h0[1] = pW[0]; h0[2] = pK[0]; h0[3] = pV[0]; h0[4] = pA[0]; h0[5] = pB[0];
    h1[0] = pR[CDIM]; h1[1] = pW[CDIM]; h1[2] = pK[CDIM]; h1[3] = pV[CDIM]; h1[4] = pA[CDIM]; h1[5] = pB[CDIM];
#pragma unroll
    for (int j = 0; j < 6; ++j) { stg[0][j][lane] = h0[j]; stg[1][j][lane] = h1[j]; }
    gA[0] = pR[2 * CDIM]; gA[1] = pW[2 * CDIM]; gA[2] = pK[2 * CDIM];
    gA[3] = pV[2 * CDIM]; gA[4] = pA[2 * CDIM]; gA[5] = pB[2 * CDIM];
    gB[0] = pR[3 * CDIM]; gB[1] = pW[3 * CDIM]; gB[2] = pK[3 * CDIM];
    gB[3] = pV[3 * CDIM]; gB[4] = pA[3 * CDIM]; gB[5] = pB[3 * CDIM];
  }
  // operand register sets: a-set = even steps, b-set = odd steps
  f32x4 aR, aW, aK, aA, aB; float aVV;
  f32x4 bR, bW, bK, bA, bB; float bVV;
  // init a-set <- slot 0 (t0), written in prologue (in-order DS)
  aR = *(const f32x4*)&stg[0][0][kk0];
  aW = *(const f32x4*)&stg[0][1][kk0];
  aK = *(const f32x4*)&stg[0][2][kk0];
  aA = *(const f32x4*)&stg[0][4][kk0];
  aB = *(const f32x4*)&stg[0][5][kk0];
  aVV = stg[0][3][gv];
  float pox = 0.f;                            // deferred o partial (prev step)
#define SCAN_STEP(T, G, SR,SW,SK,SA,SB,SVV, NR,NW,NK,NA,NB,NVV, FIRST) do {    \
    f32x4 _sv = SA * s0;                                                       \
    float _sa = _sv[0] + _sv[1] + _sv[2] + _sv[3];                             \
    { const int _np = ((T) + 1) & 3;        /* prefetch next-step operands */  \
      NR = *(const f32x4*)&stg[_np][0][kk0];                                   \
      NW = *(const f32x4*)&stg[_np][1][kk0];                                   \
      NK = *(const f32x4*)&stg[_np][2][kk0];                                   \
      NA = *(const f32x4*)&stg[_np][4][kk0];                                   \
      NB = *(const f32x4*)&stg[_np][5][kk0];                                   \
      NVV = stg[_np][3][gv]; }                                                 \
    float _po = pox;                                                           \
    _sa = redrot<0x124>(_sa); _po = redrot<0x124>(_po);                        \
    _sa = redrot<0x128>(_sa); _po = redrot<0x128>(_po);                        \
    _sa = red16(_sa, evr);    _po = red16(_po, evr);                           \
    _sa = red32(_sa, lhf);    _po = red32(_po, lhf);                           \
    if (!(FIRST) && lane < 4) Obp[(size_t)((T) - 1) * CDIM] = _po;             \
    { const int _ws = ((T) + 2) & 3;                                           \
      stg[_ws][0][lane] = G[0]; stg[_ws][1][lane] = G[1];                      \
      stg[_ws][2][lane] = G[2]; stg[_ws][3][lane] = G[3];                      \
      stg[_ws][4][lane] = G[4]; stg[_ws][5][lane] = G[5];                      \
      const size_t _to = (size_t)(((T) + 4 < T_LEN) ? (T) + 4 : T_LEN - 1) * CDIM; \
      G[0] = pR[_to]; G[1] = pW[_to]; G[2] = pK[_to];                          \
      G[3] = pV[_to]; G[4] = pA[_to]; G[5] = pB[_to]; }                        \
    s0 = s0 * SW + _sa * SB + SVV * SK;                                        \
    f32x4 _ov = s0 * SR;                                                       \
    pox = _ov[0] + _ov[1] + _ov[2] + _ov[3];                                   \
  } while (0)
#define SCAN_STEP_I(...) SCAN_STEP(__VA_ARGS__)
#define ASET aR,aW,aK,aA,aB,aVV
#define BSET bR,bW,bK,bA,bB,bVV
  SCAN_STEP_I(0, gA, ASET, BSET, true);
  SCAN_STEP_I(1, gB, BSET, ASET, false);
  for (int t = 2; t < T_LEN; t += 2) {
    SCAN_STEP_I(t, gA, ASET, BSET, false);
    SCAN_STEP_I(t + 1, gB, BSET, ASET, false);
  }
#undef SCAN_STEP
#undef SCAN_STEP_I
#undef ASET
#undef BSET
  {   // flush o_{T_LEN-1}
    float _po = pox;
    _po = redrot<0x124>(_po);
    _po = redrot<0x128>(_po);
    _po = red16(_po, evr);
    _po = red32(_po, lhf);
    if (lane < 4) Obp[(size_t)(T_LEN - 1) * CDIM] = _po;
  }
  float* sfp = Sf + (((size_t)(b * 32 + h)) * 64 + gv) * 64 + kk0;
  *(f32x4*)sfp = s0;
}

// ---------------- GroupNorm + bonus + gate -> bf16 A for out-proj ----------------
__global__ __launch_bounds__(256) void k_gn(
    const float* __restrict__ Ob, const float* __restrict__ Rb,
    const float* __restrict__ Kb, const float* __restrict__ Vb,
    const float* __restrict__ Gb, const float* __restrict__ rk,
    const float* __restrict__ gw, const float* __restrict__ gb2,
    unsigned short* __restrict__ Aout) {
  int gwv = blockIdx.x * 4 + (threadIdx.x >> 6);
  int lane = threadIdx.x & 63;
  int m = gwv >> 5, h = gwv & 31;
  int c = h * 64 + lane;
  size_t idx = (size_t)m * CDIM + c;
  float o = Ob[idx], r = Rb[idx], k = Kb[idx], v = Vb[idx], g = Gb[idx];
  float t1 = o, t2 = o * o, t3 = r * k * rk[c];
#pragma unroll
  for (int off = 32; off; off >>= 1) {
    t1 += __shfl_xor(t1, off);
    t2 += __shfl_xor(t2, off);
    t3 += __shfl_xor(t3, off);
  }
  float mean = t1 * (1.f / 64.f);
  float var = t2 * (1.f / 64.f) - mean * mean;
  float og = (o - mean) * rsqrtf(var + 6.4e-4f) * gw[c] + gb2[c];  // eps=1e-5*64
  og += t3 * v;
  Aout[idx] = f2bf(og * g);
}

// ---------------- launch ----------------
extern "C" void kernel_launch(void* const* d_in, const int* in_sizes, int n_in,
                              void* d_out, int out_size, void* d_ws, size_t ws_size,
                              hipStream_t stream) {
  (void)in_sizes; (void)n_in; (void)out_size; (void)ws_size;
  const float* x      = (const float*)d_in[0];
  const float* vfirst = (const float*)d_in[1];
  const float* shift  = (const float*)d_in[2];
  const float* wkv0   = (const float*)d_in[3];
  const float* xr_c   = (const float*)d_in[4];
  const float* xw_c   = (const float*)d_in[5];
  const float* xk_c   = (const float*)d_in[6];
  const float* xv_c   = (const float*)d_in[7];
  const float* xa_c   = (const float*)d_in[8];
  const float* xg_c   = (const float*)d_in[9];
  const float* w0     = (const float*)d_in[10];
  const float* w1     = (const float*)d_in[11];
  const float* w2     = (const float*)d_in[12];
  const float* a0     = (const float*)d_in[13];
  const float* a1     = (const float*)d_in[14];
  const float* a2     = (const float*)d_in[15];
  const float* v0     = (const float*)d_in[16];
  const float* v1     = (const float*)d_in[17];
  const float* v2     = (const float*)d_in[18];
  const float* g1     = (const float*)d_in[19];
  const float* g2     = (const float*)d_in[20];
  const float* k_k    = (const float*)d_in[21];
  const float* k_a    = (const float*)d_in[22];
  const float* r_k    = (const float*)d_in[23];
  const float* W_r    = (const float*)d_in[24];
  const float* W_k    = (const float*)d_in[25];
  const float* W_v    = (const float*)d_in[26];
  const float* W_o    = (const float*)d_in[27];
  const float* gn_w   = (const float*)d_in[28];
  const float* gn_b   = (const float*)d_in[29];
  char* ws = (char*)d_ws;
  auto BF = [&](size_t o) { return (unsigned short*)(ws + o); };
  auto FP = [&](size_t o) { return (float*)(ws + o); };

  // weights -> bf16 (one launch; 1048576 float4-chunks PER matrix)
  { Conv4 cb{W_r, W_k, W_v, W_o, BF(oWr), BF(oWk), BF(oWv), BF(oWo)};
    k_conv4<<<dim3(4096, 4), 256, 0, stream>>>(cb, 1048576); }
  // small weights -> transposed, zero-padded bf16 (8 jobs, one launch)
  { TpJobs jt{};
    jt.src[0] = w1; jt.dst[0] = BF(oW1T); jt.sR[0] = 2048; jt.sC[0] = 96;   jt.dR[0] = 128;  jt.dC[0] = 2048;
    jt.src[1] = a1; jt.dst[1] = BF(oA1T); jt.sR[1] = 2048; jt.sC[1] = 96;   jt.dR[1] = 128;  jt.dC[1] = 2048;
    jt.src[2] = v1; jt.dst[2] = BF(oV1T); jt.sR[2] = 2048; jt.sC[2] = 64;   jt.dR[2] = 128;  jt.dC[2] = 2048;
    jt.src[3] = g1; jt.dst[3] = BF(oG1T); jt.sR[3] = 2048; jt.sC[3] = 256;  jt.dR[3] = 256;  jt.dC[3] = 2048;
    jt.src[4] = w2; jt.dst[4] = BF(oW2T); jt.sR[4] = 96;   jt.sC[4] = 2048; jt.dR[4] = 2048; jt.dC[4] = 128;
    jt.src[5] = a2; jt.dst[5] = BF(oA2T); jt.sR[5] = 96;   jt.sC[5] = 2048; jt.dR[5] = 2048; jt.dC[5] = 128;
    jt.src[6] = v2; jt.dst[6] = BF(oV2T); jt.sR[6] = 64;   jt.sC[6] = 2048; jt.dR[6] = 2048; jt.dC[6] = 128;
    jt.src[7] = g2; jt.dst[7] = BF(oG2T); jt.sR[7] = 256;  jt.sC[7] = 2048; jt.dR[7] = 2048; jt.dC[7] = 256;
    k_tp8<<<dim3(2048, 8), 256, 0, stream>>>(jt); }
  // token shift + mixes
  k_mix<<<4096, 256, 0, stream>>>(x, shift, xr_c, xw_c, xk_c, xv_c, xa_c, xg_c,
                                  BF(oXr), BF(oXw), BF(oXk), BF(oXv), BF(oXa), BF(oXg));
  // r, k, v projections (batched via blockIdx.z)
  { GemmBatch gb{};
    gb.j[0] = {BF(oXr), BF(oWr), FP(oR), 0, 2048, 2048};
    gb.j[1] = {BF(oXk), BF(oWk), FP(oK), 0, 2048, 2048};
    gb.j[2] = {BF(oXv), BF(oWv), FP(oV), 0, 2048, 2048};
    k_gemm_nt<<<dim3(16, 16, 3), 256, 0, stream>>>(gb, 2048); }
  // low-rank stage 1 (w/a/v N=128 + gate N=256) in ONE launch, K=2048
  { GemmBatch gb{};
    gb.j[0] = {BF(oXw), BF(oW1T), BF(oHw), 2, 128, 128};   // tanh
    gb.j[1] = {BF(oXa), BF(oA1T), BF(oHa), 1, 128, 128};
    gb.j[2] = {BF(oXv), BF(oV1T), BF(oHv), 1, 128, 128};
    gb.j[3] = {BF(oXg), BF(oG1T), BF(oHg), 3, 256, 256};   // sigmoid
    k_gemm_nt<<<dim3(2, 16, 4), 256, 0, stream>>>(gb, 2048); }
  // low-rank stage 2 (K=128)
  { GemmBatch gb{};
    gb.j[0] = {BF(oHw), BF(oW2T), FP(oWW), 0, 2048, 2048};
    gb.j[1] = {BF(oHa), BF(oA2T), FP(oAA), 0, 2048, 2048};
    gb.j[2] = {BF(oHv), BF(oV2T), FP(oBB), 0, 2048, 2048};
    k_gemm_nt<<<dim3(16, 16, 3), 256, 0, stream>>>(gb, 128); }
  // gate stage 2 (K=256)
  { GemmBatch gb{};
    gb.j[0] = {BF(oHg), BF(oG2T), FP(oG), 0, 2048, 2048};
    k_gemm_nt<<<dim3(16, 16, 1), 256, 0, stream>>>(gb, 256); }
  // elementwise post (decay, a, v-blend, kk-normalize, k update)
  k_post<<<16384, 256, 0, stream>>>(FP(oK), FP(oV), FP(oWW), FP(oAA), FP(oBB),
                                    vfirst, w0, a0, v0, k_k, k_a);
  // recurrence: 1024 single-wave blocks (4 v-rows each)
  k_scan<<<1024, 64, 0, stream>>>(FP(oR), FP(oWW), FP(oK), FP(oV), FP(oAA), FP(oBB),
                                  wkv0, FP(oO), (float*)d_out + MC);
  // groupnorm + bonus + gate
  k_gn<<<16384, 256, 0, stream>>>(FP(oO), FP(oR), FP(oK), FP(oV), FP(oG),
                                  r_k, gn_w, gn_b, BF(oAout));
  // output projection -> d_out
  { GemmBatch gb{};
    gb.j[0] = {BF(oAout), BF(oWo), d_out, 0, 2048, 2048};
    k_gemm_nt<<<dim3(16, 16, 1), 256, 0, stream>>>(gb, 2048); }
}

// Round 17
// 585.174 us; speedup vs baseline: 1.0138x; 1.0138x over previous
//
#include <hip/hip_runtime.h>
#include <stdint.h>

typedef __attribute__((ext_vector_type(4))) float f32x4;
typedef __attribute__((ext_vector_type(8))) __bf16 bf16x8;

#define DEVINL __device__ __forceinline__

// ---------------- sizes ----------------
constexpr int T_LEN = 1024;
constexpr int CDIM  = 2048;
constexpr int MROWS = 2048;               // B*T
constexpr size_t MC = (size_t)MROWS * CDIM;

// ---------------- ws offsets (bytes) ----------------
constexpr size_t SZ_BF  = MC * 2;
constexpr size_t SZ_F32 = MC * 4;
constexpr size_t oXr  = 0;
constexpr size_t oXw  = oXr + SZ_BF;
constexpr size_t oXk  = oXw + SZ_BF;
constexpr size_t oXv  = oXk + SZ_BF;
constexpr size_t oXa  = oXv + SZ_BF;
constexpr size_t oXg  = oXa + SZ_BF;
constexpr size_t oWr  = oXg + SZ_BF;
constexpr size_t oWk  = oWr + SZ_BF;
constexpr size_t oWv  = oWk + SZ_BF;
constexpr size_t oWo  = oWv + SZ_BF;
constexpr size_t oW1T = oWo + SZ_BF;          // [128][2048] bf16 (pad rows>=96 zero)
constexpr size_t oA1T = oW1T + 524288;
constexpr size_t oV1T = oA1T + 524288;        // [128][2048] (pad>=64 zero)
constexpr size_t oG1T = oV1T + 524288;        // [256][2048]
constexpr size_t oW2T = oG1T + 1048576;       // [2048][128] (pad cols>=96 zero)
constexpr size_t oA2T = oW2T + 524288;
constexpr size_t oV2T = oA2T + 524288;
constexpr size_t oG2T = oV2T + 524288;        // [2048][256]
constexpr size_t oHw  = oG2T + 1048576;       // [2048][128] bf16
constexpr size_t oHa  = oHw + 524288;
constexpr size_t oHv  = oHa + 524288;
constexpr size_t oHg  = oHv + 524288;         // [2048][256]
constexpr size_t oR   = oHg + 1048576;        // fp32 [M][C]
constexpr size_t oK   = oR  + SZ_F32;
constexpr size_t oV   = oK  + SZ_F32;
constexpr size_t oWW  = oV  + SZ_F32;
constexpr size_t oAA  = oWW + SZ_F32;
constexpr size_t oBB  = oAA + SZ_F32;
constexpr size_t oG   = oBB + SZ_F32;
constexpr size_t oO   = oG  + SZ_F32;
constexpr size_t oAout= oO  + SZ_F32;         // bf16 [M][C]

// ---------------- helpers ----------------
DEVINL unsigned short f2bf(float f) {
  uint32_t u = __builtin_bit_cast(uint32_t, f);
  u += 0x7fffu + ((u >> 16) & 1u);            // RNE
  return (unsigned short)(u >> 16);
}
DEVINL void st_bf4(unsigned short* p, f32x4 v) {
  ushort4 o;
  o.x = f2bf(v[0]); o.y = f2bf(v[1]); o.z = f2bf(v[2]); o.w = f2bf(v[3]);
  *(ushort4*)p = o;
}
DEVINL void gload16(const void* g, void* l) {
  __builtin_amdgcn_global_load_lds(
      (const __attribute__((address_space(1))) unsigned int*)g,
      (__attribute__((address_space(3))) unsigned int*)l, 16, 0, 0);
}

// ---- VALU-speed cross-lane reduce hops (register-only; no LDS pipe) ----
// DPP control MUST be a compile-time constant -> template (R15 lesson).
template <int CTL>
DEVINL float redrot(float x) {               // 0x121/0x122/0x124/0x128 = row_ror:1/2/4/8
  int y = __builtin_amdgcn_update_dpp(0, __builtin_bit_cast(int, x),
                                      CTL, 0xF, 0xF, true);
  return x + __builtin_bit_cast(float, y);
}
// full 16-lane-row sum via 4 rotations (sum is rotation-composable)
DEVINL float redrow16(float x) {
  x = redrot<0x128>(x); x = redrot<0x124>(x);
  x = redrot<0x122>(x); x = redrot<0x121>(x);
  return x;
}
// xor16: v_permlane16_swap_b32 (HW-verified in R14)
#if __has_builtin(__builtin_amdgcn_permlane16_swap)
DEVINL float red16(float x, bool evenrow) {
  unsigned xi = __builtin_bit_cast(unsigned, x);
  auto r = __builtin_amdgcn_permlane16_swap(xi, xi, false, false);
  unsigned oth = evenrow ? (unsigned)r[1] : (unsigned)r[0];
  return x + __builtin_bit_cast(float, oth);
}
#else
DEVINL float red16(float x, bool) { return x + __shfl_xor(x, 16); }
#endif
// xor32: v_permlane32_swap_b32 (HW-verified in R14)
#if __has_builtin(__builtin_amdgcn_permlane32_swap)
DEVINL float red32(float x, bool lowhalf) {
  unsigned xi = __builtin_bit_cast(unsigned, x);
  auto r = __builtin_amdgcn_permlane32_swap(xi, xi, false, false);
  unsigned oth = lowhalf ? (unsigned)r[1] : (unsigned)r[0];
  return x + __builtin_bit_cast(float, oth);
}
#else
DEVINL float red32(float x, bool) { return x + __shfl_xor(x, 32); }
#endif

// ---------------- fp32 -> bf16 convert, 4 matrices per launch ----------------
struct Conv4 { const float* s0; const float* s1; const float* s2; const float* s3;
               unsigned short* d0; unsigned short* d1; unsigned short* d2; unsigned short* d3; };
__global__ void k_conv4(Conv4 c, int n4) {
  int i = blockIdx.x * 256 + threadIdx.x;
  if (i >= n4) return;
  const float* s = (blockIdx.y == 0) ? c.s0 : (blockIdx.y == 1) ? c.s1
                   : (blockIdx.y == 2) ? c.s2 : c.s3;
  unsigned short* d = (blockIdx.y == 0) ? c.d0 : (blockIdx.y == 1) ? c.d1
                      : (blockIdx.y == 2) ? c.d2 : c.d3;
  f32x4 v = *(const f32x4*)(s + (size_t)i * 4);
  st_bf4(d + (size_t)i * 4, v);
}

// ---------------- transpose + zero-pad, 8 jobs in one launch ----------------
struct TpJobs {
  const float* src[8];
  unsigned short* dst[8];
  int sR[8]; int sC[8]; int dR[8]; int dC[8];
};
__global__ void k_tp8(TpJobs jt) {
  const int j = blockIdx.y;
  const int n = jt.dR[j] * jt.dC[j];
  int i = blockIdx.x * 256 + threadIdx.x;
  if (i >= n) return;
  const int dC = jt.dC[j], sR = jt.sR[j], sC = jt.sC[j];
  int r = i / dC, c = i - r * dC;
  float v = (r < sC && c < sR) ? jt.src[j][(size_t)c * sC + r] : 0.f;
  jt.dst[j][i] = f2bf(v);
}

// ---------------- token shift + 6 mixes -> bf16 ----------------
__global__ void k_mix(const float* __restrict__ x, const float* __restrict__ shift,
                      const float* __restrict__ cr, const float* __restrict__ cw,
                      const float* __restrict__ ck, const float* __restrict__ cv,
                      const float* __restrict__ ca, const float* __restrict__ cg,
                      unsigned short* __restrict__ Xr, unsigned short* __restrict__ Xw,
                      unsigned short* __restrict__ Xk, unsigned short* __restrict__ Xv,
                      unsigned short* __restrict__ Xa, unsigned short* __restrict__ Xg) {
  int i = blockIdx.x * 256 + threadIdx.x;      // one float4 per thread
  size_t e = (size_t)i * 4;
  int m = (int)(e >> 11);
  int c = (int)(e & 2047);
  int t = m & (T_LEN - 1);
  int b = m >> 10;
  f32x4 xc = *(const f32x4*)(x + e);
  f32x4 pv = (t == 0) ? *(const f32x4*)(shift + (size_t)b * CDIM + c)
                      : *(const f32x4*)(x + e - CDIM);
  f32x4 xx = pv - xc;
  st_bf4(Xr + e, xc + xx * (*(const f32x4*)(cr + c)));
  st_bf4(Xw + e, xc + xx * (*(const f32x4*)(cw + c)));
  st_bf4(Xk + e, xc + xx * (*(const f32x4*)(ck + c)));
  st_bf4(Xv + e, xc + xx * (*(const f32x4*)(cv + c)));
  st_bf4(Xa + e, xc + xx * (*(const f32x4*)(ca + c)));
  st_bf4(Xg + e, xc + xx * (*(const f32x4*)(cg + c)));
}

// ---------------- NT bf16 GEMM: C[m][n] = sum_k A[m][k]*B[n][k] ----------------
// m97 structure + XCD-aware bijective tile swizzle (nwg % 8 == 0 for all grids:
// swz = (fid&7)*(nwg/8) + fid>>3 -- transpose of 8 x q, each XCD gets a
// contiguous tile band => A/B panel L2 reuse).
struct GemmJob { const unsigned short* A; const unsigned short* B; void* C; int epi; int ldc; int n; };
struct GemmBatch { GemmJob j[4]; };

__global__ __launch_bounds__(256) void k_gemm_nt(GemmBatch gb, int K) {
  const GemmJob jb = gb.j[blockIdx.z];
  const int gx = gridDim.x;
  const int nwg = gx * gridDim.y;
  const int fid = blockIdx.y * gx + blockIdx.x;
  const int swz = (fid & 7) * (nwg >> 3) + (fid >> 3);   // bijective (nwg%8==0)
  const int rowB = (swz / gx) * 128;
  const int colB = (swz % gx) * 128;
  if (colB >= jb.n) return;
  const int ldc = jb.ldc;
  __shared__ __align__(16) unsigned short As[128 * 32];
  __shared__ __align__(16) unsigned short Bs[128 * 32];
  const int tid  = threadIdx.x;
  const int lane = tid & 63;
  const int wv   = tid >> 6;
  const int wm = wv >> 1, wn = wv & 1;
  // staging: 8 chunks of 1KB (16 rows x 64B); wave wv owns chunks wv and wv+4
  const size_t rsb = (size_t)K * 2;           // row stride bytes
  const int c0 = wv, c1 = wv + 4;
  const char* Ag0 = (const char*)jb.A + (size_t)(rowB + c0 * 16 + (lane >> 2)) * rsb + (lane & 3) * 16;
  const char* Ag1 = (const char*)jb.A + (size_t)(rowB + c1 * 16 + (lane >> 2)) * rsb + (lane & 3) * 16;
  const char* Bg0 = (const char*)jb.B + (size_t)(colB + c0 * 16 + (lane >> 2)) * rsb + (lane & 3) * 16;
  const char* Bg1 = (const char*)jb.B + (size_t)(colB + c1 * 16 + (lane >> 2)) * rsb + (lane & 3) * 16;
  unsigned short* Al0 = As + c0 * 512;        // wave-uniform LDS base
  unsigned short* Al1 = As + c1 * 512;
  unsigned short* Bl0 = Bs + c0 * 512;
  unsigned short* Bl1 = Bs + c1 * 512;
  f32x4 acc[4][4];
#pragma unroll
  for (int mi = 0; mi < 4; ++mi)
#pragma unroll
    for (int ni = 0; ni < 4; ++ni) acc[mi][ni] = (f32x4){0.f, 0.f, 0.f, 0.f};
  const int KT = K >> 5;
  const int fr = lane & 15, fk = (lane >> 4) * 8;
  for (int kt = 0; kt < KT; ++kt) {
    __syncthreads();                          // prior-iter LDS reads complete
    gload16(Ag0, Al0); gload16(Ag1, Al1);
    gload16(Bg0, Bl0); gload16(Bg1, Bl1);
    Ag0 += 64; Ag1 += 64; Bg0 += 64; Bg1 += 64;
    __syncthreads();                          // drains vmcnt -> LDS tile ready
    bf16x8 af[4], bfv[4];
#pragma unroll
    for (int mi = 0; mi < 4; ++mi)
      af[mi] = *(const bf16x8*)&As[(wm * 64 + mi * 16 + fr) * 32 + fk];
#pragma unroll
    for (int ni = 0; ni < 4; ++ni)
      bfv[ni] = *(const bf16x8*)&Bs[(wn * 64 + ni * 16 + fr) * 32 + fk];
#pragma unroll
    for (int mi = 0; mi < 4; ++mi)
#pragma unroll
      for (int ni = 0; ni < 4; ++ni)
        acc[mi][ni] = __builtin_amdgcn_mfma_f32_16x16x32_bf16(af[mi], bfv[ni], acc[mi][ni], 0, 0, 0);
  }
  // epilogue: C/D layout col=lane&15, row=(lane>>4)*4+j
  const int er = (lane >> 4) * 4, ec = lane & 15;
  if (jb.epi == 0) {
    float* Cf = (float*)jb.C;
#pragma unroll
    for (int mi = 0; mi < 4; ++mi)
#pragma unroll
      for (int ni = 0; ni < 4; ++ni) {
        int row0 = rowB + wm * 64 + mi * 16 + er;
        int col  = colB + wn * 64 + ni * 16 + ec;
#pragma unroll
        for (int j = 0; j < 4; ++j)
          Cf[(size_t)(row0 + j) * ldc + col] = acc[mi][ni][j];
      }
  } else {
    unsigned short* Cb = (unsigned short*)jb.C;
#pragma unroll
    for (int mi = 0; mi < 4; ++mi)
#pragma unroll
      for (int ni = 0; ni < 4; ++ni) {
        int row0 = rowB + wm * 64 + mi * 16 + er;
        int col  = colB + wn * 64 + ni * 16 + ec;
#pragma unroll
        for (int j = 0; j < 4; ++j) {
          float val = acc[mi][ni][j];
          if (jb.epi == 2) val = tanhf(val);
          else if (jb.epi == 3) val = 1.f / (1.f + __expf(-val));
          Cb[(size_t)(row0 + j) * ldc + col] = f2bf(val);
        }
      }
  }
}

// ---------------- post-GEMM elementwise + per-head kk normalize ----------------
// Vectorized: f32x4/lane; wave = 4 heads (16 lanes/head); per-head reduce via
// 4 DPP row-rotations (full 16-lane sum). grid 4096 x 256.
__global__ __launch_bounds__(256) void k_post(
    float* __restrict__ Kb, float* __restrict__ Vb, float* __restrict__ Wb,
    float* __restrict__ Ab, float* __restrict__ Bb,
    const float* __restrict__ vf, const float* __restrict__ w0,
    const float* __restrict__ a0, const float* __restrict__ v0,
    const float* __restrict__ kkc, const float* __restrict__ kac) {
  const int wv = threadIdx.x >> 6, lane = threadIdx.x & 63;
  const int gw = blockIdx.x * 4 + wv;         // [0, 16384)
  const int m = gw >> 3, q = gw & 7;
  const int c = q * 256 + lane * 4;
  const size_t idx = (size_t)m * CDIM + c;
  f32x4 kraw = *(const f32x4*)(Kb + idx);
  f32x4 vraw = *(const f32x4*)(Vb + idx);
  f32x4 wlr  = *(const f32x4*)(Wb + idx);
  f32x4 alr  = *(const f32x4*)(Ab + idx);
  f32x4 vlr  = *(const f32x4*)(Bb + idx);
  f32x4 vf4  = *(const f32x4*)(vf + idx);
  f32x4 w04  = *(const f32x4*)(w0 + c);
  f32x4 a04  = *(const f32x4*)(a0 + c);
  f32x4 v04  = *(const f32x4*)(v0 + c);
  f32x4 kkc4 = *(const f32x4*)(kkc + c);
  f32x4 kac4 = *(const f32x4*)(kac + c);
  f32x4 wdec, aa, vv, kk, kn;
#pragma unroll
  for (int j = 0; j < 4; ++j) {
    float z = w04[j] + wlr[j];
    float sg = 1.f / (1.f + __expf(-z));
    wdec[j] = __expf(-0.60653065971f * sg);   // exp(-exp(-softplus(-z)-0.5))
    aa[j] = 1.f / (1.f + __expf(-(a04[j] + alr[j])));
    float vgate = 1.f / (1.f + __expf(-(v04[j] + vlr[j])));
    vv[j] = vraw[j] + (vf4[j] - vraw[j]) * vgate;
    kk[j] = kraw[j] * kkc4[j];
    kn[j] = kraw[j] * (1.f + (aa[j] - 1.f) * kac4[j]);
  }
  float s2 = kk[0] * kk[0] + kk[1] * kk[1] + kk[2] * kk[2] + kk[3] * kk[3];
  s2 = redrow16(s2);                          // full head (16-lane row) sum
  float inv = 1.f / fmaxf(sqrtf(s2), 1e-12f);
  f32x4 nkk = kk * inv;
  *(f32x4*)(Wb + idx) = wdec;
  *(f32x4*)(Vb + idx) = vv;
  *(f32x4*)(Kb + idx) = kn;
  *(f32x4*)(Ab + idx) = -nkk;
  *(f32x4*)(Bb + idx) = nkk * aa;
}

// ---------------- RWKV-7 recurrence (R16-exact, FROZEN @ ~287us) ----------------
__global__ __launch_bounds__(64) void k_scan(
    const float* __restrict__ Rb, const float* __restrict__ Wb,
    const float* __restrict__ Kb, const float* __restrict__ Vb,
    const float* __restrict__ Ab, const float* __restrict__ Bb,
    const float* __restrict__ S0, float* __restrict__ Ob,
    float* __restrict__ Sf) {
  const int bid = blockIdx.x;
  const int bh = bid & 63, vo = bid >> 6;     // vo in 0..15; stride 64 => same XCD
  const int b = bh >> 5, h = bh & 31;
  const int lane = threadIdx.x;
  const int vr = lane & 3;
  const int kq = lane >> 2;
  const int gv = vo * 4 + vr;                 // global v-row in head
  const int kk0 = kq * 4;                     // 4 k per lane
  const bool evr = ((lane >> 4) & 1) == 0;    // even 16-lane row
  const bool lhf = lane < 32;                 // lower 32-lane half
  __shared__ __align__(16) float stg[4][6][64];
  const size_t rowBase = (size_t)b * T_LEN * CDIM;
  const size_t colBase = (size_t)h * 64;
  const float* pR = Rb + rowBase + colBase + lane;
  const float* pW = Wb + rowBase + colBase + lane;
  const float* pK = Kb + rowBase + colBase + lane;
  const float* pV = Vb + rowBase + colBase + lane;
  const float* pA = Ab + rowBase + colBase + lane;
  const float* pB = Bb + rowBase + colBase + lane;
  float* Obp = Ob + rowBase + colBase + vo * 4 + lane;   // valid for lane<4
  f32x4 s0;
  {
    const float* sp = S0 + (((size_t)(b * 32 + h)) * 64 + gv) * 64 + kk0;
    s0 = *(const f32x4*)sp;
  }
  float gA[6], gB[6];
  {   // prologue: stg[0]<-t0, stg[1]<-t1, gA<-t2, gB<-t3
    float h0[6], h1[6];
    h0[0] = pR[0]; h0[1] = pW[0]; h0[2] = pK[0]; h0[3] = pV[0]; h0[4] = pA[0]; h0[5] = pB[0];
    h1[0] = pR[CDIM]; h1[1] = pW[CDIM]; h1[2] = pK[CDIM]; h1[3] = pV[CDIM]; h1[4] = pA[CDIM]; h1[5] = pB[CDIM];
#pragma unroll
    for (int j = 0; j < 6; ++j) { stg[0][j][lane] = h0[j]; stg[1][j][lane] = h1[j]; }
    gA[0] = pR[2 * CDIM]; gA[1] = pW[2 * CDIM]; gA[2] = pK[2 * CDIM];
    gA[3] = pV[2 * CDIM]; gA[4] = pA[2 * CDIM]; gA[5] = pB[2 * CDIM];
    gB[0] = pR[3 * CDIM]; gB[1] = pW[3 * CDIM]; gB[2] = pK[3 * CDIM];
    gB[3] = pV[3 * CDIM]; gB[4] = pA[3 * CDIM]; gB[5] = pB[3 * CDIM];
  }
  // operand register sets: a-set = even steps, b-set = odd steps
  f32x4 aR, aW, aK, aA, aB; float aVV;
  f32x4 bR, bW, bK, bA, bB; float bVV;
  // init a-set <- slot 0 (t0), written in prologue (in-order DS)
  aR = *(const f32x4*)&stg[0][0][kk0];
  aW = *(const f32x4*)&stg[0][1][kk0];
  aK = *(const f32x4*)&stg[0][2][kk0];
  aA = *(const f32x4*)&stg[0][4][kk0];
  aB = *(const f32x4*)&stg[0][5][kk0];
  aVV = stg[0][3][gv];
  float pox = 0.f;                            // deferred o partial (prev step)
#define SCAN_STEP(T, G, SR,SW,SK,SA,SB,SVV, NR,NW,NK,NA,NB,NVV, FIRST) do {    \
    f32x4 _sv = SA * s0;                                                       \
    float _sa = _sv[0] + _sv[1] + _sv[2] + _sv[3];                             \
    { const int _np = ((T) + 1) & 3;        /* prefetch next-step operands */  \
      NR = *(const f32x4*)&stg[_np][0][kk0];                                   \
      NW = *(const f32x4*)&stg[_np][1][kk0];                                   \
      NK = *(const f32x4*)&stg[_np][2][kk0];                                   \
      NA = *(const f32x4*)&stg[_np][4][kk0];                                   \
      NB = *(const f32x4*)&stg[_np][5][kk0];                                   \
      NVV = stg[_np][3][gv]; }                                                 \
    float _po = pox;                                                           \
    _sa = redrot<0x124>(_sa); _po = redrot<0x124>(_po);                        \
    _sa = redrot<0x128>(_sa); _po = redrot<0x128>(_po);                        \
    _sa = red16(_sa, evr);    _po = red16(_po, evr);                           \
    _sa = red32(_sa, lhf);    _po = red32(_po, lhf);                           \
    if (!(FIRST) && lane < 4) Obp[(size_t)((T) - 1) * CDIM] = _po;             \
    { const int _ws = ((T) + 2) & 3;                                           \
      stg[_ws][0][lane] = G[0]; stg[_ws][1][lane] = G[1];                      \
      stg[_ws][2][lane] = G[2]; stg[_ws][3][lane] = G[3];                      \
      stg[_ws][4][lane] = G[4]; stg[_ws][5][lane] = G[5];                      \
      const size_t _to = (size_t)(((T) + 4 < T_LEN) ? (T) + 4 : T_LEN - 1) * CDIM; \
      G[0] = pR[_to]; G[1] = pW[_to]; G[2] = pK[_to];                          \
      G[3] = pV[_to]; G[4] = pA[_to]; G[5] = pB[_to]; }                        \
    s0 = s0 * SW + _sa * SB + SVV * SK;                                        \
    f32x4 _ov = s0 * SR;                                                       \
    pox = _ov[0] + _ov[1] + _ov[2] + _ov[3];                                   \
  } while (0)
#define SCAN_STEP_I(...) SCAN_STEP(__VA_ARGS__)
#define ASET aR,aW,aK,aA,aB,aVV
#define BSET bR,bW,bK,bA,bB,bVV
  SCAN_STEP_I(0, gA, ASET, BSET, true);
  SCAN_STEP_I(1, gB, BSET, ASET, false);
  for (int t = 2; t < T_LEN; t += 2) {
    SCAN_STEP_I(t, gA, ASET, BSET, false);
    SCAN_STEP_I(t + 1, gB, BSET, ASET, false);
  }
#undef SCAN_STEP
#undef SCAN_STEP_I
#undef ASET
#undef BSET
  {   // flush o_{T_LEN-1}
    float _po = pox;
    _po = redrot<0x124>(_po);
    _po = redrot<0x128>(_po);
    _po = red16(_po, evr);
    _po = red32(_po, lhf);
    if (lane < 4) Obp[(size_t)(T_LEN - 1) * CDIM] = _po;
  }
  float* sfp = Sf + (((size_t)(b * 32 + h)) * 64 + gv) * 64 + kk0;
  *(f32x4*)sfp = s0;
}

// ---------------- GroupNorm + bonus + gate -> bf16 A for out-proj ----------------
// Vectorized: f32x4/lane; wave = 4 heads; per-head reduce via DPP row-rotations.
__global__ __launch_bounds__(256) void k_gn(
    const float* __restrict__ Ob, const float* __restrict__ Rb,
    const float* __restrict__ Kb, const float* __restrict__ Vb,
    const float* __restrict__ Gb, const float* __restrict__ rk,
    const float* __restrict__ gw, const float* __restrict__ gb2,
    unsigned short* __restrict__ Aout) {
  const int wv = threadIdx.x >> 6, lane = threadIdx.x & 63;
  const int gwv = blockIdx.x * 4 + wv;        // [0, 16384)
  const int m = gwv >> 3, q = gwv & 7;
  const int c = q * 256 + lane * 4;
  const size_t idx = (size_t)m * CDIM + c;
  f32x4 o  = *(const f32x4*)(Ob + idx);
  f32x4 r  = *(const f32x4*)(Rb + idx);
  f32x4 k  = *(const f32x4*)(Kb + idx);
  f32x4 v  = *(const f32x4*)(Vb + idx);
  f32x4 g  = *(const f32x4*)(Gb + idx);
  f32x4 rk4 = *(const f32x4*)(rk + c);
  f32x4 gw4 = *(const f32x4*)(gw + c);
  f32x4 gb4 = *(const f32x4*)(gb2 + c);
  float t1 = o[0] + o[1] + o[2] + o[3];
  float t2 = o[0]*o[0] + o[1]*o[1] + o[2]*o[2] + o[3]*o[3];
  f32x4 rkv = r * k * rk4;
  float t3 = rkv[0] + rkv[1] + rkv[2] + rkv[3];
  t1 = redrow16(t1);
  t2 = redrow16(t2);
  t3 = redrow16(t3);
  float mean = t1 * (1.f / 64.f);
  float var = t2 * (1.f / 64.f) - mean * mean;
  float rstd = rsqrtf(var + 6.4e-4f);         // eps = 1e-5 * 64
  f32x4 og = (o - mean) * rstd * gw4 + gb4 + t3 * v;
  st_bf4(Aout + idx, og * g);
}

// ---------------- launch ----------------
extern "C" void kernel_launch(void* const* d_in, const int* in_sizes, int n_in,
                              void* d_out, int out_size, void* d_ws, size_t ws_size,
                              hipStream_t stream) {
  (void)in_sizes; (void)n_in; (void)out_size; (void)ws_size;
  const float* x      = (const float*)d_in[0];
  const float* vfirst = (const float*)d_in[1];
  const float* shift  = (const float*)d_in[2];
  const float* wkv0   = (const float*)d_in[3];
  const float* xr_c   = (const float*)d_in[4];
  const float* xw_c   = (const float*)d_in[5];
  const float* xk_c   = (const float*)d_in[6];
  const float* xv_c   = (const float*)d_in[7];
  const float* xa_c   = (const float*)d_in[8];
  const float* xg_c   = (const float*)d_in[9];
  const float* w0     = (const float*)d_in[10];
  const float* w1     = (const float*)d_in[11];
  const float* w2     = (const float*)d_in[12];
  const float* a0     = (const float*)d_in[13];
  const float* a1     = (const float*)d_in[14];
  const float* a2     = (const float*)d_in[15];
  const float* v0     = (const float*)d_in[16];
  const float* v1     = (const float*)d_in[17];
  const float* v2     = (const float*)d_in[18];
  const float* g1     = (const float*)d_in[19];
  const float* g2     = (const float*)d_in[20];
  const float* k_k    = (const float*)d_in[21];
  const float* k_a    = (const float*)d_in[22];
  const float* r_k    = (const float*)d_in[23];
  const float* W_r    = (const float*)d_in[24];
  const float* W_k    = (const float*)d_in[25];
  const float* W_v    = (const float*)d_in[26];
  const float* W_o    = (const float*)d_in[27];
  const float* gn_w   = (const float*)d_in[28];
  const float* gn_b   = (const float*)d_in[29];
  char* ws = (char*)d_ws;
  auto BF = [&](size_t o) { return (unsigned short*)(ws + o); };
  auto FP = [&](size_t o) { return (float*)(ws + o); };

  // weights -> bf16 (one launch; 1048576 float4-chunks PER matrix)
  { Conv4 cb{W_r, W_k, W_v, W_o, BF(oWr), BF(oWk), BF(oWv), BF(oWo)};
    k_conv4<<<dim3(4096, 4), 256, 0, stream>>>(cb, 1048576); }
  // small weights -> transposed, zero-padded bf16 (8 jobs, one launch)
  { TpJobs jt{};
    jt.src[0] = w1; jt.dst[0] = BF(oW1T); jt.sR[0] = 2048; jt.sC[0] = 96;   jt.dR[0] = 128;  jt.dC[0] = 2048;
    jt.src[1] = a1; jt.dst[1] = BF(oA1T); jt.sR[1] = 2048; jt.sC[1] = 96;   jt.dR[1] = 128;  jt.dC[1] = 2048;
    jt.src[2] = v1; jt.dst[2] = BF(oV1T); jt.sR[2] = 2048; jt.sC[2] = 64;   jt.dR[2] = 128;  jt.dC[2] = 2048;
    jt.src[3] = g1; jt.dst[3] = BF(oG1T); jt.sR[3] = 2048; jt.sC[3] = 256;  jt.dR[3] = 256;  jt.dC[3] = 2048;
    jt.src[4] = w2; jt.dst[4] = BF(oW2T); jt.sR[4] = 96;   jt.sC[4] = 2048; jt.dR[4] = 2048; jt.dC[4] = 128;
    jt.src[5] = a2; jt.dst[5] = BF(oA2T); jt.sR[5] = 96;   jt.sC[5] = 2048; jt.dR[5] = 2048; jt.dC[5] = 128;
    jt.src[6] = v2; jt.dst[6] = BF(oV2T); jt.sR[6] = 64;   jt.sC[6] = 2048; jt.dR[6] = 2048; jt.dC[6] = 128;
    jt.src[7] = g2; jt.dst[7] = BF(oG2T); jt.sR[7] = 256;  jt.sC[7] = 2048; jt.dR[7] = 2048; jt.dC[7] = 256;
    k_tp8<<<dim3(2048, 8), 256, 0, stream>>>(jt); }
  // token shift + mixes
  k_mix<<<4096, 256, 0, stream>>>(x, shift, xr_c, xw_c, xk_c, xv_c, xa_c, xg_c,
                                  BF(oXr), BF(oXw), BF(oXk), BF(oXv), BF(oXa), BF(oXg));
  // r, k, v projections (batched via blockIdx.z)
  { GemmBatch gb{};
    gb.j[0] = {BF(oXr), BF(oWr), FP(oR), 0, 2048, 2048};
    gb.j[1] = {BF(oXk), BF(oWk), FP(oK), 0, 2048, 2048};
    gb.j[2] = {BF(oXv), BF(oWv), FP(oV), 0, 2048, 2048};
    k_gemm_nt<<<dim3(16, 16, 3), 256, 0, stream>>>(gb, 2048); }
  // low-rank stage 1 (w/a/v N=128 + gate N=256) in ONE launch, K=2048
  { GemmBatch gb{};
    gb.j[0] = {BF(oXw), BF(oW1T), BF(oHw), 2, 128, 128};   // tanh
    gb.j[1] = {BF(oXa), BF(oA1T), BF(oHa), 1, 128, 128};
    gb.j[2] = {BF(oXv), BF(oV1T), BF(oHv), 1, 128, 128};
    gb.j[3] = {BF(oXg), BF(oG1T), BF(oHg), 3, 256, 256};   // sigmoid
    k_gemm_nt<<<dim3(2, 16, 4), 256, 0, stream>>>(gb, 2048); }
  // low-rank stage 2 (K=128)
  { GemmBatch gb{};
    gb.j[0] = {BF(oHw), BF(oW2T), FP(oWW), 0, 2048, 2048};
    gb.j[1] = {BF(oHa), BF(oA2T), FP(oAA), 0, 2048, 2048};
    gb.j[2] = {BF(oHv), BF(oV2T), FP(oBB), 0, 2048, 2048};
    k_gemm_nt<<<dim3(16, 16, 3), 256, 0, stream>>>(gb, 128); }
  // gate stage 2 (K=256)
  { GemmBatch gb{};
    gb.j[0] = {BF(oHg), BF(oG2T), FP(oG), 0, 2048, 2048};
    k_gemm_nt<<<dim3(16, 16, 1), 256, 0, stream>>>(gb, 256); }
  // elementwise post (decay, a, v-blend, kk-normalize, k update) -- vectorized
  k_post<<<4096, 256, 0, stream>>>(FP(oK), FP(oV), FP(oWW), FP(oAA), FP(oBB),
                                   vfirst, w0, a0, v0, k_k, k_a);
  // recurrence: 1024 single-wave blocks (4 v-rows each)
  k_scan<<<1024, 64, 0, stream>>>(FP(oR), FP(oWW), FP(oK), FP(oV), FP(oAA), FP(oBB),
                                  wkv0, FP(oO), (float*)d_out + MC);
  // groupnorm + bonus + gate -- vectorized
  k_gn<<<4096, 256, 0, stream>>>(FP(oO), FP(oR), FP(oK), FP(oV), FP(oG),
                                 r_k, gn_w, gn_b, BF(oAout));
  // output projection -> d_out
  { GemmBatch gb{};
    gb.j[0] = {BF(oAout), BF(oWo), d_out, 0, 2048, 2048};
    k_gemm_nt<<<dim3(16, 16, 1), 256, 0, stream>>>(gb, 2048); }
}

// Round 18
// 568.703 us; speedup vs baseline: 1.0432x; 1.0290x over previous
//
#include <hip/hip_runtime.h>
#include <stdint.h>

typedef __attribute__((ext_vector_type(4))) float f32x4;
typedef __attribute__((ext_vector_type(8))) __bf16 bf16x8;

#define DEVINL __device__ __forceinline__

// ---------------- sizes ----------------
constexpr int T_LEN = 1024;
constexpr int CDIM  = 2048;
constexpr int MROWS = 2048;               // B*T
constexpr size_t MC = (size_t)MROWS * CDIM;

// ---------------- ws offsets (bytes) ----------------
constexpr size_t SZ_BF  = MC * 2;
constexpr size_t SZ_F32 = MC * 4;
constexpr size_t oXr  = 0;
constexpr size_t oXw  = oXr + SZ_BF;
constexpr size_t oXk  = oXw + SZ_BF;
constexpr size_t oXv  = oXk + SZ_BF;
constexpr size_t oXa  = oXv + SZ_BF;
constexpr size_t oXg  = oXa + SZ_BF;
constexpr size_t oWr  = oXg + SZ_BF;
constexpr size_t oWk  = oWr + SZ_BF;
constexpr size_t oWv  = oWk + SZ_BF;
constexpr size_t oWo  = oWv + SZ_BF;
constexpr size_t oW1T = oWo + SZ_BF;          // [128][2048] bf16 (pad rows>=96 zero)
constexpr size_t oA1T = oW1T + 524288;
constexpr size_t oV1T = oA1T + 524288;        // [128][2048] (pad>=64 zero)
constexpr size_t oG1T = oV1T + 524288;        // [256][2048]
constexpr size_t oW2T = oG1T + 1048576;       // [2048][128] (pad cols>=96 zero)
constexpr size_t oA2T = oW2T + 524288;
constexpr size_t oV2T = oA2T + 524288;
constexpr size_t oG2T = oV2T + 524288;        // [2048][256]
constexpr size_t oHw  = oG2T + 1048576;       // [2048][128] bf16
constexpr size_t oHa  = oHw + 524288;
constexpr size_t oHv  = oHa + 524288;
constexpr size_t oHg  = oHv + 524288;         // [2048][256]
constexpr size_t oR   = oHg + 1048576;        // fp32 [M][C]
constexpr size_t oK   = oR  + SZ_F32;
constexpr size_t oV   = oK  + SZ_F32;
constexpr size_t oWW  = oV  + SZ_F32;
constexpr size_t oAA  = oWW + SZ_F32;
constexpr size_t oBB  = oAA + SZ_F32;
constexpr size_t oG   = oBB + SZ_F32;
constexpr size_t oO   = oG  + SZ_F32;
constexpr size_t oAout= oO  + SZ_F32;         // bf16 [M][C]

// ---------------- helpers ----------------
DEVINL unsigned short f2bf(float f) {
  uint32_t u = __builtin_bit_cast(uint32_t, f);
  u += 0x7fffu + ((u >> 16) & 1u);            // RNE
  return (unsigned short)(u >> 16);
}
DEVINL void st_bf4(unsigned short* p, f32x4 v) {
  ushort4 o;
  o.x = f2bf(v[0]); o.y = f2bf(v[1]); o.z = f2bf(v[2]); o.w = f2bf(v[3]);
  *(ushort4*)p = o;
}
DEVINL void gload16(const void* g, void* l) {
  __builtin_amdgcn_global_load_lds(
      (const __attribute__((address_space(1))) unsigned int*)g,
      (__attribute__((address_space(3))) unsigned int*)l, 16, 0, 0);
}

// ---- VALU-speed cross-lane reduce hops (register-only; no LDS pipe) ----
// DPP control MUST be a compile-time constant -> template (R15 lesson).
template <int CTL>
DEVINL float redrot(float x) {               // 0x121/0x122/0x124/0x128 = row_ror:1/2/4/8
  int y = __builtin_amdgcn_update_dpp(0, __builtin_bit_cast(int, x),
                                      CTL, 0xF, 0xF, true);
  return x + __builtin_bit_cast(float, y);
}
// full 16-lane-row sum via 4 rotations (sum is rotation-composable)
DEVINL float redrow16(float x) {
  x = redrot<0x128>(x); x = redrot<0x124>(x);
  x = redrot<0x122>(x); x = redrot<0x121>(x);
  return x;
}
// xor16: v_permlane16_swap_b32 (HW-verified in R14)
#if __has_builtin(__builtin_amdgcn_permlane16_swap)
DEVINL float red16(float x, bool evenrow) {
  unsigned xi = __builtin_bit_cast(unsigned, x);
  auto r = __builtin_amdgcn_permlane16_swap(xi, xi, false, false);
  unsigned oth = evenrow ? (unsigned)r[1] : (unsigned)r[0];
  return x + __builtin_bit_cast(float, oth);
}
#else
DEVINL float red16(float x, bool) { return x + __shfl_xor(x, 16); }
#endif
// xor32: v_permlane32_swap_b32 (HW-verified in R14)
#if __has_builtin(__builtin_amdgcn_permlane32_swap)
DEVINL float red32(float x, bool lowhalf) {
  unsigned xi = __builtin_bit_cast(unsigned, x);
  auto r = __builtin_amdgcn_permlane32_swap(xi, xi, false, false);
  unsigned oth = lowhalf ? (unsigned)r[1] : (unsigned)r[0];
  return x + __builtin_bit_cast(float, oth);
}
#else
DEVINL float red32(float x, bool) { return x + __shfl_xor(x, 32); }
#endif

// ---------------- fp32 -> bf16 convert, 4 matrices per launch ----------------
struct Conv4 { const float* s0; const float* s1; const float* s2; const float* s3;
               unsigned short* d0; unsigned short* d1; unsigned short* d2; unsigned short* d3; };
__global__ void k_conv4(Conv4 c, int n4) {
  int i = blockIdx.x * 256 + threadIdx.x;
  if (i >= n4) return;
  const float* s = (blockIdx.y == 0) ? c.s0 : (blockIdx.y == 1) ? c.s1
                   : (blockIdx.y == 2) ? c.s2 : c.s3;
  unsigned short* d = (blockIdx.y == 0) ? c.d0 : (blockIdx.y == 1) ? c.d1
                      : (blockIdx.y == 2) ? c.d2 : c.d3;
  f32x4 v = *(const f32x4*)(s + (size_t)i * 4);
  st_bf4(d + (size_t)i * 4, v);
}

// ---------------- transpose + zero-pad, 8 jobs in one launch ----------------
struct TpJobs {
  const float* src[8];
  unsigned short* dst[8];
  int sR[8]; int sC[8]; int dR[8]; int dC[8];
};
__global__ void k_tp8(TpJobs jt) {
  const int j = blockIdx.y;
  const int n = jt.dR[j] * jt.dC[j];
  int i = blockIdx.x * 256 + threadIdx.x;
  if (i >= n) return;
  const int dC = jt.dC[j], sR = jt.sR[j], sC = jt.sC[j];
  int r = i / dC, c = i - r * dC;
  float v = (r < sC && c < sR) ? jt.src[j][(size_t)c * sC + r] : 0.f;
  jt.dst[j][i] = f2bf(v);
}

// ---------------- token shift + 6 mixes -> bf16 ----------------
__global__ void k_mix(const float* __restrict__ x, const float* __restrict__ shift,
                      const float* __restrict__ cr, const float* __restrict__ cw,
                      const float* __restrict__ ck, const float* __restrict__ cv,
                      const float* __restrict__ ca, const float* __restrict__ cg,
                      unsigned short* __restrict__ Xr, unsigned short* __restrict__ Xw,
                      unsigned short* __restrict__ Xk, unsigned short* __restrict__ Xv,
                      unsigned short* __restrict__ Xa, unsigned short* __restrict__ Xg) {
  int i = blockIdx.x * 256 + threadIdx.x;      // one float4 per thread
  size_t e = (size_t)i * 4;
  int m = (int)(e >> 11);
  int c = (int)(e & 2047);
  int t = m & (T_LEN - 1);
  int b = m >> 10;
  f32x4 xc = *(const f32x4*)(x + e);
  f32x4 pv = (t == 0) ? *(const f32x4*)(shift + (size_t)b * CDIM + c)
                      : *(const f32x4*)(x + e - CDIM);
  f32x4 xx = pv - xc;
  st_bf4(Xr + e, xc + xx * (*(const f32x4*)(cr + c)));
  st_bf4(Xw + e, xc + xx * (*(const f32x4*)(cw + c)));
  st_bf4(Xk + e, xc + xx * (*(const f32x4*)(ck + c)));
  st_bf4(Xv + e, xc + xx * (*(const f32x4*)(cv + c)));
  st_bf4(Xa + e, xc + xx * (*(const f32x4*)(ca + c)));
  st_bf4(Xg + e, xc + xx * (*(const f32x4*)(cg + c)));
}

// ---------------- NT bf16 GEMM: C[m][n] = sum_k A[m][k]*B[n][k] ----------------
// m97 structure + XCD-aware bijective tile swizzle. Per-job K/ldc/n (R18):
// jobs with different K and N batch in one launch; blocks with colB >= n
// early-exit (dead blocks cost ~us; lets tiny-N stage-1 ride inside QKV).
struct GemmJob { const unsigned short* A; const unsigned short* B; void* C;
                 int epi; int ldc; int n; int K; };
struct GemmBatch { GemmJob j[8]; };

__global__ __launch_bounds__(256) void k_gemm_nt(GemmBatch gb) {
  const GemmJob jb = gb.j[blockIdx.z];
  const int K = jb.K;
  const int gx = gridDim.x;
  const int nwg = gx * gridDim.y;
  const int fid = blockIdx.y * gx + blockIdx.x;
  const int swz = (fid & 7) * (nwg >> 3) + (fid >> 3);   // bijective (nwg%8==0)
  const int rowB = (swz / gx) * 128;
  const int colB = (swz % gx) * 128;
  if (colB >= jb.n) return;
  const int ldc = jb.ldc;
  __shared__ __align__(16) unsigned short As[128 * 32];
  __shared__ __align__(16) unsigned short Bs[128 * 32];
  const int tid  = threadIdx.x;
  const int lane = tid & 63;
  const int wv   = tid >> 6;
  const int wm = wv >> 1, wn = wv & 1;
  // staging: 8 chunks of 1KB (16 rows x 64B); wave wv owns chunks wv and wv+4
  const size_t rsb = (size_t)K * 2;           // row stride bytes (A,B row stride == K)
  const int c0 = wv, c1 = wv + 4;
  const char* Ag0 = (const char*)jb.A + (size_t)(rowB + c0 * 16 + (lane >> 2)) * rsb + (lane & 3) * 16;
  const char* Ag1 = (const char*)jb.A + (size_t)(rowB + c1 * 16 + (lane >> 2)) * rsb + (lane & 3) * 16;
  const char* Bg0 = (const char*)jb.B + (size_t)(colB + c0 * 16 + (lane >> 2)) * rsb + (lane & 3) * 16;
  const char* Bg1 = (const char*)jb.B + (size_t)(colB + c1 * 16 + (lane >> 2)) * rsb + (lane & 3) * 16;
  unsigned short* Al0 = As + c0 * 512;        // wave-uniform LDS base
  unsigned short* Al1 = As + c1 * 512;
  unsigned short* Bl0 = Bs + c0 * 512;
  unsigned short* Bl1 = Bs + c1 * 512;
  f32x4 acc[4][4];
#pragma unroll
  for (int mi = 0; mi < 4; ++mi)
#pragma unroll
    for (int ni = 0; ni < 4; ++ni) acc[mi][ni] = (f32x4){0.f, 0.f, 0.f, 0.f};
  const int KT = K >> 5;
  const int fr = lane & 15, fk = (lane >> 4) * 8;
  for (int kt = 0; kt < KT; ++kt) {
    __syncthreads();                          // prior-iter LDS reads complete
    gload16(Ag0, Al0); gload16(Ag1, Al1);
    gload16(Bg0, Bl0); gload16(Bg1, Bl1);
    Ag0 += 64; Ag1 += 64; Bg0 += 64; Bg1 += 64;
    __syncthreads();                          // drains vmcnt -> LDS tile ready
    bf16x8 af[4], bfv[4];
#pragma unroll
    for (int mi = 0; mi < 4; ++mi)
      af[mi] = *(const bf16x8*)&As[(wm * 64 + mi * 16 + fr) * 32 + fk];
#pragma unroll
    for (int ni = 0; ni < 4; ++ni)
      bfv[ni] = *(const bf16x8*)&Bs[(wn * 64 + ni * 16 + fr) * 32 + fk];
#pragma unroll
    for (int mi = 0; mi < 4; ++mi)
#pragma unroll
      for (int ni = 0; ni < 4; ++ni)
        acc[mi][ni] = __builtin_amdgcn_mfma_f32_16x16x32_bf16(af[mi], bfv[ni], acc[mi][ni], 0, 0, 0);
  }
  // epilogue: C/D layout col=lane&15, row=(lane>>4)*4+j
  const int er = (lane >> 4) * 4, ec = lane & 15;
  if (jb.epi == 0) {
    float* Cf = (float*)jb.C;
#pragma unroll
    for (int mi = 0; mi < 4; ++mi)
#pragma unroll
      for (int ni = 0; ni < 4; ++ni) {
        int row0 = rowB + wm * 64 + mi * 16 + er;
        int col  = colB + wn * 64 + ni * 16 + ec;
#pragma unroll
        for (int j = 0; j < 4; ++j)
          Cf[(size_t)(row0 + j) * ldc + col] = acc[mi][ni][j];
      }
  } else {
    unsigned short* Cb = (unsigned short*)jb.C;
#pragma unroll
    for (int mi = 0; mi < 4; ++mi)
#pragma unroll
      for (int ni = 0; ni < 4; ++ni) {
        int row0 = rowB + wm * 64 + mi * 16 + er;
        int col  = colB + wn * 64 + ni * 16 + ec;
#pragma unroll
        for (int j = 0; j < 4; ++j) {
          float val = acc[mi][ni][j];
          if (jb.epi == 2) val = tanhf(val);
          else if (jb.epi == 3) val = 1.f / (1.f + __expf(-val));
          Cb[(size_t)(row0 + j) * ldc + col] = f2bf(val);
        }
      }
  }
}

// ---------------- post-GEMM elementwise + per-head kk normalize ----------------
// Vectorized: f32x4/lane; wave = 4 heads (16 lanes/head); per-head reduce via
// 4 DPP row-rotations (full 16-lane sum). grid 4096 x 256.
__global__ __launch_bounds__(256) void k_post(
    float* __restrict__ Kb, float* __restrict__ Vb, float* __restrict__ Wb,
    float* __restrict__ Ab, float* __restrict__ Bb,
    const float* __restrict__ vf, const float* __restrict__ w0,
    const float* __restrict__ a0, const float* __restrict__ v0,
    const float* __restrict__ kkc, const float* __restrict__ kac) {
  const int wv = threadIdx.x >> 6, lane = threadIdx.x & 63;
  const int gw = blockIdx.x * 4 + wv;         // [0, 16384)
  const int m = gw >> 3, q = gw & 7;
  const int c = q * 256 + lane * 4;
  const size_t idx = (size_t)m * CDIM + c;
  f32x4 kraw = *(const f32x4*)(Kb + idx);
  f32x4 vraw = *(const f32x4*)(Vb + idx);
  f32x4 wlr  = *(const f32x4*)(Wb + idx);
  f32x4 alr  = *(const f32x4*)(Ab + idx);
  f32x4 vlr  = *(const f32x4*)(Bb + idx);
  f32x4 vf4  = *(const f32x4*)(vf + idx);
  f32x4 w04  = *(const f32x4*)(w0 + c);
  f32x4 a04  = *(const f32x4*)(a0 + c);
  f32x4 v04  = *(const f32x4*)(v0 + c);
  f32x4 kkc4 = *(const f32x4*)(kkc + c);
  f32x4 kac4 = *(const f32x4*)(kac + c);
  f32x4 wdec, aa, vv, kk, kn;
#pragma unroll
  for (int j = 0; j < 4; ++j) {
    float z = w04[j] + wlr[j];
    float sg = 1.f / (1.f + __expf(-z));
    wdec[j] = __expf(-0.60653065971f * sg);   // exp(-exp(-softplus(-z)-0.5))
    aa[j] = 1.f / (1.f + __expf(-(a04[j] + alr[j])));
    float vgate = 1.f / (1.f + __expf(-(v04[j] + vlr[j])));
    vv[j] = vraw[j] + (vf4[j] - vraw[j]) * vgate;
    kk[j] = kraw[j] * kkc4[j];
    kn[j] = kraw[j] * (1.f + (aa[j] - 1.f) * kac4[j]);
  }
  float s2 = kk[0] * kk[0] + kk[1] * kk[1] + kk[2] * kk[2] + kk[3] * kk[3];
  s2 = redrow16(s2);                          // full head (16-lane row) sum
  float inv = 1.f / fmaxf(sqrtf(s2), 1e-12f);
  f32x4 nkk = kk * inv;
  *(f32x4*)(Wb + idx) = wdec;
  *(f32x4*)(Vb + idx) = vv;
  *(f32x4*)(Kb + idx) = kn;
  *(f32x4*)(Ab + idx) = -nkk;
  *(f32x4*)(Bb + idx) = nkk * aa;
}

// ---------------- RWKV-7 recurrence (R16-exact, FROZEN @ ~288us) ----------------
__global__ __launch_bounds__(64) void k_scan(
    const float* __restrict__ Rb, const float* __restrict__ Wb,
    const float* __restrict__ Kb, const float* __restrict__ Vb,
    const float* __restrict__ Ab, const float* __restrict__ Bb,
    const float* __restrict__ S0, float* __restrict__ Ob,
    float* __restrict__ Sf) {
  const int bid = blockIdx.x;
  const int bh = bid & 63, vo = bid >> 6;     // vo in 0..15; stride 64 => same XCD
  const int b = bh >> 5, h = bh & 31;
  const int lane = threadIdx.x;
  const int vr = lane & 3;
  const int kq = lane >> 2;
  const int gv = vo * 4 + vr;                 // global v-row in head
  const int kk0 = kq * 4;                     // 4 k per lane
  const bool evr = ((lane >> 4) & 1) == 0;    // even 16-lane row
  const bool lhf = lane < 32;                 // lower 32-lane half
  __shared__ __align__(16) float stg[4][6][64];
  const size_t rowBase = (size_t)b * T_LEN * CDIM;
  const size_t colBase = (size_t)h * 64;
  const float* pR = Rb + rowBase + colBase + lane;
  const float* pW = Wb + rowBase + colBase + lane;
  const float* pK = Kb + rowBase + colBase + lane;
  const float* pV = Vb + rowBase + colBase + lane;
  const float* pA = Ab + rowBase + colBase + lane;
  const float* pB = Bb + rowBase + colBase + lane;
  float* Obp = Ob + rowBase + colBase + vo * 4 + lane;   // valid for lane<4
  f32x4 s0;
  {
    const float* sp = S0 + (((size_t)(b * 32 + h)) * 64 + gv) * 64 + kk0;
    s0 = *(const f32x4*)sp;
  }
  float gA[6], gB[6];
  {   // prologue: stg[0]<-t0, stg[1]<-t1, gA<-t2, gB<-t3
    float h0[6], h1[6];
    h0[0] = pR[0]; h0[1] = pW[0]; h0[2] = pK[0]; h0[3] = pV[0]; h0[4] = pA[0]; h0[5] = pB[0];
    h1[0] = pR[CDIM]; h1[1] = pW[CDIM]; h1[2] = pK[CDIM]; h1[3] = pV[CDIM]; h1[4] = pA[CDIM]; h1[5] = pB[CDIM];
#pragma unroll
    for (int j = 0; j < 6; ++j) { stg[0][j][lane] = h0[j]; stg[1][j][lane] = h1[j]; }
    gA[0] = pR[2 * CDIM]; gA[1] = pW[2 * CDIM]; gA[2] = pK[2 * CDIM];
    gA[3] = pV[2 * CDIM]; gA[4] = pA[2 * CDIM]; gA[5] = pB[2 * CDIM];
    gB[0] = pR[3 * CDIM]; gB[1] = pW[3 * CDIM]; gB[2] = pK[3 * CDIM];
    gB[3] = pV[3 * CDIM]; gB[4] = pA[3 * CDIM]; gB[5] = pB[3 * CDIM];
  }
  // operand register sets: a-set = even steps, b-set = odd steps
  f32x4 aR, aW, aK, aA, aB; float aVV;
  f32x4 bR, bW, bK, bA, bB; float bVV;
  // init a-set <- slot 0 (t0), written in prologue (in-order DS)
  aR = *(const f32x4*)&stg[0][0][kk0];
  aW = *(const f32x4*)&stg[0][1][kk0];
  aK = *(const f32x4*)&stg[0][2][kk0];
  aA = *(const f32x4*)&stg[0][4][kk0];
  aB = *(const f32x4*)&stg[0][5][kk0];
  aVV = stg[0][3][gv];
  float pox = 0.f;                            // deferred o partial (prev step)
#define SCAN_STEP(T, G, SR,SW,SK,SA,SB,SVV, NR,NW,NK,NA,NB,NVV, FIRST) do {    \
    f32x4 _sv = SA * s0;                                                       \
    float _sa = _sv[0] + _sv[1] + _sv[2] + _sv[3];                             \
    { const int _np = ((T) + 1) & 3;        /* prefetch next-step operands */  \
      NR = *(const f32x4*)&stg[_np][0][kk0];                                   \
      NW = *(const f32x4*)&stg[_np][1][kk0];                                   \
      NK = *(const f32x4*)&stg[_np][2][kk0];                                   \
      NA = *(const f32x4*)&stg[_np][4][kk0];                                   \
      NB = *(const f32x4*)&stg[_np][5][kk0];                                   \
      NVV = stg[_np][3][gv]; }                                                 \
    float _po = pox;                                                           \
    _sa = redrot<0x124>(_sa); _po = redrot<0x124>(_po);                        \
    _sa = redrot<0x128>(_sa); _po = redrot<0x128>(_po);                        \
    _sa = red16(_sa, evr);    _po = red16(_po, evr);                           \
    _sa = red32(_sa, lhf);    _po = red32(_po, lhf);                           \
    if (!(FIRST) && lane < 4) Obp[(size_t)((T) - 1) * CDIM] = _po;             \
    { const int _ws = ((T) + 2) & 3;                                           \
      stg[_ws][0][lane] = G[0]; stg[_ws][1][lane] = G[1];                      \
      stg[_ws][2][lane] = G[2]; stg[_ws][3][lane] = G[3];                      \
      stg[_ws][4][lane] = G[4]; stg[_ws][5][lane] = G[5];                      \
      const size_t _to = (size_t)(((T) + 4 < T_LEN) ? (T) + 4 : T_LEN - 1) * CDIM; \
      G[0] = pR[_to]; G[1] = pW[_to]; G[2] = pK[_to];                          \
      G[3] = pV[_to]; G[4] = pA[_to]; G[5] = pB[_to]; }                        \
    s0 = s0 * SW + _sa * SB + SVV * SK;                                        \
    f32x4 _ov = s0 * SR;                                                       \
    pox = _ov[0] + _ov[1] + _ov[2] + _ov[3];                                   \
  } while (0)
#define SCAN_STEP_I(...) SCAN_STEP(__VA_ARGS__)
#define ASET aR,aW,aK,aA,aB,aVV
#define BSET bR,bW,bK,bA,bB,bVV
  SCAN_STEP_I(0, gA, ASET, BSET, true);
  SCAN_STEP_I(1, gB, BSET, ASET, false);
  for (int t = 2; t < T_LEN; t += 2) {
    SCAN_STEP_I(t, gA, ASET, BSET, false);
    SCAN_STEP_I(t + 1, gB, BSET, ASET, false);
  }
#undef SCAN_STEP
#undef SCAN_STEP_I
#undef ASET
#undef BSET
  {   // flush o_{T_LEN-1}
    float _po = pox;
    _po = redrot<0x124>(_po);
    _po = redrot<0x128>(_po);
    _po = red16(_po, evr);
    _po = red32(_po, lhf);
    if (lane < 4) Obp[(size_t)(T_LEN - 1) * CDIM] = _po;
  }
  float* sfp = Sf + (((size_t)(b * 32 + h)) * 64 + gv) * 64 + kk0;
  *(f32x4*)sfp = s0;
}

// ---------------- GroupNorm + bonus + gate -> bf16 A for out-proj ----------------
// Vectorized: f32x4/lane; wave = 4 heads; per-head reduce via DPP row-rotations.
__global__ __launch_bounds__(256) void k_gn(
    const float* __restrict__ Ob, const float* __restrict__ Rb,
    const float* __restrict__ Kb, const float* __restrict__ Vb,
    const float* __restrict__ Gb, const float* __restrict__ rk,
    const float* __restrict__ gw, const float* __restrict__ gb2,
    unsigned short* __restrict__ Aout) {
  const int wv = threadIdx.x >> 6, lane = threadIdx.x & 63;
  const int gwv = blockIdx.x * 4 + wv;        // [0, 16384)
  const int m = gwv >> 3, q = gwv & 7;
  const int c = q * 256 + lane * 4;
  const size_t idx = (size_t)m * CDIM + c;
  f32x4 o  = *(const f32x4*)(Ob + idx);
  f32x4 r  = *(const f32x4*)(Rb + idx);
  f32x4 k  = *(const f32x4*)(Kb + idx);
  f32x4 v  = *(const f32x4*)(Vb + idx);
  f32x4 g  = *(const f32x4*)(Gb + idx);
  f32x4 rk4 = *(const f32x4*)(rk + c);
  f32x4 gw4 = *(const f32x4*)(gw + c);
  f32x4 gb4 = *(const f32x4*)(gb2 + c);
  float t1 = o[0] + o[1] + o[2] + o[3];
  float t2 = o[0]*o[0] + o[1]*o[1] + o[2]*o[2] + o[3]*o[3];
  f32x4 rkv = r * k * rk4;
  float t3 = rkv[0] + rkv[1] + rkv[2] + rkv[3];
  t1 = redrow16(t1);
  t2 = redrow16(t2);
  t3 = redrow16(t3);
  float mean = t1 * (1.f / 64.f);
  float var = t2 * (1.f / 64.f) - mean * mean;
  float rstd = rsqrtf(var + 6.4e-4f);         // eps = 1e-5 * 64
  f32x4 og = (o - mean) * rstd * gw4 + gb4 + t3 * v;
  st_bf4(Aout + idx, og * g);
}

// ---------------- launch ----------------
extern "C" void kernel_launch(void* const* d_in, const int* in_sizes, int n_in,
                              void* d_out, int out_size, void* d_ws, size_t ws_size,
                              hipStream_t stream) {
  (void)in_sizes; (void)n_in; (void)out_size; (void)ws_size;
  const float* x      = (const float*)d_in[0];
  const float* vfirst = (const float*)d_in[1];
  const float* shift  = (const float*)d_in[2];
  const float* wkv0   = (const float*)d_in[3];
  const float* xr_c   = (const float*)d_in[4];
  const float* xw_c   = (const float*)d_in[5];
  const float* xk_c   = (const float*)d_in[6];
  const float* xv_c   = (const float*)d_in[7];
  const float* xa_c   = (const float*)d_in[8];
  const float* xg_c   = (const float*)d_in[9];
  const float* w0     = (const float*)d_in[10];
  const float* w1     = (const float*)d_in[11];
  const float* w2     = (const float*)d_in[12];
  const float* a0     = (const float*)d_in[13];
  const float* a1     = (const float*)d_in[14];
  const float* a2     = (const float*)d_in[15];
  const float* v0     = (const float*)d_in[16];
  const float* v1     = (const float*)d_in[17];
  const float* v2     = (const float*)d_in[18];
  const float* g1     = (const float*)d_in[19];
  const float* g2     = (const float*)d_in[20];
  const float* k_k    = (const float*)d_in[21];
  const float* k_a    = (const float*)d_in[22];
  const float* r_k    = (const float*)d_in[23];
  const float* W_r    = (const float*)d_in[24];
  const float* W_k    = (const float*)d_in[25];
  const float* W_v    = (const float*)d_in[26];
  const float* W_o    = (const float*)d_in[27];
  const float* gn_w   = (const float*)d_in[28];
  const float* gn_b   = (const float*)d_in[29];
  char* ws = (char*)d_ws;
  auto BF = [&](size_t o) { return (unsigned short*)(ws + o); };
  auto FP = [&](size_t o) { return (float*)(ws + o); };

  // weights -> bf16 (one launch; 1048576 float4-chunks PER matrix)
  { Conv4 cb{W_r, W_k, W_v, W_o, BF(oWr), BF(oWk), BF(oWv), BF(oWo)};
    k_conv4<<<dim3(4096, 4), 256, 0, stream>>>(cb, 1048576); }
  // small weights -> transposed, zero-padded bf16 (8 jobs, one launch)
  { TpJobs jt{};
    jt.src[0] = w1; jt.dst[0] = BF(oW1T); jt.sR[0] = 2048; jt.sC[0] = 96;   jt.dR[0] = 128;  jt.dC[0] = 2048;
    jt.src[1] = a1; jt.dst[1] = BF(oA1T); jt.sR[1] = 2048; jt.sC[1] = 96;   jt.dR[1] = 128;  jt.dC[1] = 2048;
    jt.src[2] = v1; jt.dst[2] = BF(oV1T); jt.sR[2] = 2048; jt.sC[2] = 64;   jt.dR[2] = 128;  jt.dC[2] = 2048;
    jt.src[3] = g1; jt.dst[3] = BF(oG1T); jt.sR[3] = 2048; jt.sC[3] = 256;  jt.dR[3] = 256;  jt.dC[3] = 2048;
    jt.src[4] = w2; jt.dst[4] = BF(oW2T); jt.sR[4] = 96;   jt.sC[4] = 2048; jt.dR[4] = 2048; jt.dC[4] = 128;
    jt.src[5] = a2; jt.dst[5] = BF(oA2T); jt.sR[5] = 96;   jt.sC[5] = 2048; jt.dR[5] = 2048; jt.dC[5] = 128;
    jt.src[6] = v2; jt.dst[6] = BF(oV2T); jt.sR[6] = 64;   jt.sC[6] = 2048; jt.dR[6] = 2048; jt.dC[6] = 128;
    jt.src[7] = g2; jt.dst[7] = BF(oG2T); jt.sR[7] = 256;  jt.sC[7] = 2048; jt.dR[7] = 2048; jt.dC[7] = 256;
    k_tp8<<<dim3(2048, 8), 256, 0, stream>>>(jt); }
  // token shift + mixes
  k_mix<<<4096, 256, 0, stream>>>(x, shift, xr_c, xw_c, xk_c, xv_c, xa_c, xg_c,
                                  BF(oXr), BF(oXw), BF(oXk), BF(oXv), BF(oXa), BF(oXg));
  // QKV projections + ALL stage-1 low-rank GEMMs in ONE launch (z=7).
  // Stage-1's ~64 useful blocks ride inside QKV's 768-block window.
  { GemmBatch gb{};
    gb.j[0] = {BF(oXr), BF(oWr),  FP(oR),  0, 2048, 2048, 2048};
    gb.j[1] = {BF(oXk), BF(oWk),  FP(oK),  0, 2048, 2048, 2048};
    gb.j[2] = {BF(oXv), BF(oWv),  FP(oV),  0, 2048, 2048, 2048};
    gb.j[3] = {BF(oXw), BF(oW1T), BF(oHw), 2, 128, 128, 2048};   // tanh
    gb.j[4] = {BF(oXa), BF(oA1T), BF(oHa), 1, 128, 128, 2048};
    gb.j[5] = {BF(oXv), BF(oV1T), BF(oHv), 1, 128, 128, 2048};
    gb.j[6] = {BF(oXg), BF(oG1T), BF(oHg), 3, 256, 256, 2048};   // sigmoid
    k_gemm_nt<<<dim3(16, 16, 7), 256, 0, stream>>>(gb); }
  // stage-2 low-rank (K=128) + gate stage-2 (K=256) in ONE launch (z=4)
  { GemmBatch gb{};
    gb.j[0] = {BF(oHw), BF(oW2T), FP(oWW), 0, 2048, 2048, 128};
    gb.j[1] = {BF(oHa), BF(oA2T), FP(oAA), 0, 2048, 2048, 128};
    gb.j[2] = {BF(oHv), BF(oV2T), FP(oBB), 0, 2048, 2048, 128};
    gb.j[3] = {BF(oHg), BF(oG2T), FP(oG),  0, 2048, 2048, 256};
    k_gemm_nt<<<dim3(16, 16, 4), 256, 0, stream>>>(gb); }
  // elementwise post (decay, a, v-blend, kk-normalize, k update) -- vectorized
  k_post<<<4096, 256, 0, stream>>>(FP(oK), FP(oV), FP(oWW), FP(oAA), FP(oBB),
                                   vfirst, w0, a0, v0, k_k, k_a);
  // recurrence: 1024 single-wave blocks (4 v-rows each)
  k_scan<<<1024, 64, 0, stream>>>(FP(oR), FP(oWW), FP(oK), FP(oV), FP(oAA), FP(oBB),
                                  wkv0, FP(oO), (float*)d_out + MC);
  // groupnorm + bonus + gate -- vectorized
  k_gn<<<4096, 256, 0, stream>>>(FP(oO), FP(oR), FP(oK), FP(oV), FP(oG),
                                 r_k, gn_w, gn_b, BF(oAout));
  // output projection -> d_out
  { GemmBatch gb{};
    gb.j[0] = {BF(oAout), BF(oWo), d_out, 0, 2048, 2048, 2048};
    k_gemm_nt<<<dim3(16, 16, 1), 256, 0, stream>>>(gb); }
}

// Round 19
// 562.411 us; speedup vs baseline: 1.0549x; 1.0112x over previous
//
#include <hip/hip_runtime.h>
#include <stdint.h>

typedef __attribute__((ext_vector_type(4))) float f32x4;
typedef __attribute__((ext_vector_type(8))) __bf16 bf16x8;

#define DEVINL __device__ __forceinline__

// ---------------- sizes ----------------
constexpr int T_LEN = 1024;
constexpr int CDIM  = 2048;
constexpr int MROWS = 2048;               // B*T
constexpr size_t MC = (size_t)MROWS * CDIM;

// ---------------- ws offsets (bytes) ----------------
constexpr size_t SZ_BF  = MC * 2;
constexpr size_t SZ_F32 = MC * 4;
constexpr size_t oXr  = 0;
constexpr size_t oXw  = oXr + SZ_BF;
constexpr size_t oXk  = oXw + SZ_BF;
constexpr size_t oXv  = oXk + SZ_BF;
constexpr size_t oXa  = oXv + SZ_BF;
constexpr size_t oXg  = oXa + SZ_BF;
constexpr size_t oWr  = oXg + SZ_BF;
constexpr size_t oWk  = oWr + SZ_BF;
constexpr size_t oWv  = oWk + SZ_BF;
constexpr size_t oWo  = oWv + SZ_BF;
constexpr size_t oW1T = oWo + SZ_BF;          // [128][2048] bf16 (pad rows>=96 zero)
constexpr size_t oA1T = oW1T + 524288;
constexpr size_t oV1T = oA1T + 524288;        // [128][2048] (pad>=64 zero)
constexpr size_t oG1T = oV1T + 524288;        // [256][2048]
constexpr size_t oW2T = oG1T + 1048576;       // [2048][128] (pad cols>=96 zero)
constexpr size_t oA2T = oW2T + 524288;
constexpr size_t oV2T = oA2T + 524288;
constexpr size_t oG2T = oV2T + 524288;        // [2048][256]
constexpr size_t oHw  = oG2T + 1048576;       // [2048][128] bf16
constexpr size_t oHa  = oHw + 524288;
constexpr size_t oHv  = oHa + 524288;
constexpr size_t oHg  = oHv + 524288;         // [2048][256]
constexpr size_t oR   = oHg + 1048576;        // fp32 [M][C]
constexpr size_t oK   = oR  + SZ_F32;
constexpr size_t oV   = oK  + SZ_F32;
constexpr size_t oWW  = oV  + SZ_F32;         // scan input; REUSED as out-proj partial0
constexpr size_t oAA  = oWW + SZ_F32;         // scan input; REUSED as out-proj partial1
constexpr size_t oBB  = oAA + SZ_F32;
constexpr size_t oG   = oBB + SZ_F32;
constexpr size_t oO   = oG  + SZ_F32;
constexpr size_t oAout= oO  + SZ_F32;         // bf16 [M][C]

// ---------------- helpers ----------------
DEVINL unsigned short f2bf(float f) {
  uint32_t u = __builtin_bit_cast(uint32_t, f);
  u += 0x7fffu + ((u >> 16) & 1u);            // RNE
  return (unsigned short)(u >> 16);
}
DEVINL void st_bf4(unsigned short* p, f32x4 v) {
  ushort4 o;
  o.x = f2bf(v[0]); o.y = f2bf(v[1]); o.z = f2bf(v[2]); o.w = f2bf(v[3]);
  *(ushort4*)p = o;
}
DEVINL void gload16(const void* g, void* l) {
  __builtin_amdgcn_global_load_lds(
      (const __attribute__((address_space(1))) unsigned int*)g,
      (__attribute__((address_space(3))) unsigned int*)l, 16, 0, 0);
}

// ---- VALU-speed cross-lane reduce hops (register-only; no LDS pipe) ----
template <int CTL>
DEVINL float redrot(float x) {               // 0x121/0x122/0x124/0x128 = row_ror:1/2/4/8
  int y = __builtin_amdgcn_update_dpp(0, __builtin_bit_cast(int, x),
                                      CTL, 0xF, 0xF, true);
  return x + __builtin_bit_cast(float, y);
}
DEVINL float redrow16(float x) {
  x = redrot<0x128>(x); x = redrot<0x124>(x);
  x = redrot<0x122>(x); x = redrot<0x121>(x);
  return x;
}
#if __has_builtin(__builtin_amdgcn_permlane16_swap)
DEVINL float red16(float x, bool evenrow) {
  unsigned xi = __builtin_bit_cast(unsigned, x);
  auto r = __builtin_amdgcn_permlane16_swap(xi, xi, false, false);
  unsigned oth = evenrow ? (unsigned)r[1] : (unsigned)r[0];
  return x + __builtin_bit_cast(float, oth);
}
#else
DEVINL float red16(float x, bool) { return x + __shfl_xor(x, 16); }
#endif
#if __has_builtin(__builtin_amdgcn_permlane32_swap)
DEVINL float red32(float x, bool lowhalf) {
  unsigned xi = __builtin_bit_cast(unsigned, x);
  auto r = __builtin_amdgcn_permlane32_swap(xi, xi, false, false);
  unsigned oth = lowhalf ? (unsigned)r[1] : (unsigned)r[0];
  return x + __builtin_bit_cast(float, oth);
}
#else
DEVINL float red32(float x, bool) { return x + __shfl_xor(x, 32); }
#endif

// ---------------- fp32 -> bf16 convert, 4 matrices per launch ----------------
struct Conv4 { const float* s0; const float* s1; const float* s2; const float* s3;
               unsigned short* d0; unsigned short* d1; unsigned short* d2; unsigned short* d3; };
__global__ void k_conv4(Conv4 c, int n4) {
  int i = blockIdx.x * 256 + threadIdx.x;
  if (i >= n4) return;
  const float* s = (blockIdx.y == 0) ? c.s0 : (blockIdx.y == 1) ? c.s1
                   : (blockIdx.y == 2) ? c.s2 : c.s3;
  unsigned short* d = (blockIdx.y == 0) ? c.d0 : (blockIdx.y == 1) ? c.d1
                      : (blockIdx.y == 2) ? c.d2 : c.d3;
  f32x4 v = *(const f32x4*)(s + (size_t)i * 4);
  st_bf4(d + (size_t)i * 4, v);
}

// ---------------- transpose + zero-pad, 8 jobs in one launch ----------------
struct TpJobs {
  const float* src[8];
  unsigned short* dst[8];
  int sR[8]; int sC[8]; int dR[8]; int dC[8];
};
__global__ void k_tp8(TpJobs jt) {
  const int j = blockIdx.y;
  const int n = jt.dR[j] * jt.dC[j];
  int i = blockIdx.x * 256 + threadIdx.x;
  if (i >= n) return;
  const int dC = jt.dC[j], sR = jt.sR[j], sC = jt.sC[j];
  int r = i / dC, c = i - r * dC;
  float v = (r < sC && c < sR) ? jt.src[j][(size_t)c * sC + r] : 0.f;
  jt.dst[j][i] = f2bf(v);
}

// ---------------- token shift + 6 mixes -> bf16 (8 floats/thread) ----------------
__global__ void k_mix(const float* __restrict__ x, const float* __restrict__ shift,
                      const float* __restrict__ cr, const float* __restrict__ cw,
                      const float* __restrict__ ck, const float* __restrict__ cv,
                      const float* __restrict__ ca, const float* __restrict__ cg,
                      unsigned short* __restrict__ Xr, unsigned short* __restrict__ Xw,
                      unsigned short* __restrict__ Xk, unsigned short* __restrict__ Xv,
                      unsigned short* __restrict__ Xa, unsigned short* __restrict__ Xg) {
  int i = blockIdx.x * 256 + threadIdx.x;      // two float4 per thread
  size_t e = (size_t)i * 8;
  int m = (int)(e >> 11);
  int c = (int)(e & 2047);
  int t = m & (T_LEN - 1);
  int b = m >> 10;
  f32x4 xc0 = *(const f32x4*)(x + e);
  f32x4 xc1 = *(const f32x4*)(x + e + 4);
  f32x4 pv0, pv1;
  if (t == 0) {
    pv0 = *(const f32x4*)(shift + (size_t)b * CDIM + c);
    pv1 = *(const f32x4*)(shift + (size_t)b * CDIM + c + 4);
  } else {
    pv0 = *(const f32x4*)(x + e - CDIM);
    pv1 = *(const f32x4*)(x + e - CDIM + 4);
  }
  f32x4 xx0 = pv0 - xc0, xx1 = pv1 - xc1;
#define MIX1(P, CF) do {                                                       \
    st_bf4(P + e,     xc0 + xx0 * (*(const f32x4*)(CF + c)));                  \
    st_bf4(P + e + 4, xc1 + xx1 * (*(const f32x4*)(CF + c + 4)));              \
  } while (0)
  MIX1(Xr, cr); MIX1(Xw, cw); MIX1(Xk, ck);
  MIX1(Xv, cv); MIX1(Xa, ca); MIX1(Xg, cg);
#undef MIX1
}

// ---------------- NT bf16 GEMM: C[m][n] = sum_k A[m][k]*B[n][k] ----------------
// m97 structure + XCD swizzle. Per-job K/lda/ldb/ldc/n (R19): lda/ldb decouple
// row stride from job K, enabling split-K jobs (A,B offset by koff; stride = full K).
struct GemmJob { const unsigned short* A; const unsigned short* B; void* C;
                 int epi; int ldc; int n; int K; int lda; int ldb; };
struct GemmBatch { GemmJob j[8]; };

__global__ __launch_bounds__(256) void k_gemm_nt(GemmBatch gb) {
  const GemmJob jb = gb.j[blockIdx.z];
  const int K = jb.K;
  const int gx = gridDim.x;
  const int nwg = gx * gridDim.y;
  const int fid = blockIdx.y * gx + blockIdx.x;
  const int swz = (fid & 7) * (nwg >> 3) + (fid >> 3);   // bijective (nwg%8==0)
  const int rowB = (swz / gx) * 128;
  const int colB = (swz % gx) * 128;
  if (colB >= jb.n) return;
  const int ldc = jb.ldc;
  __shared__ __align__(16) unsigned short As[128 * 32];
  __shared__ __align__(16) unsigned short Bs[128 * 32];
  const int tid  = threadIdx.x;
  const int lane = tid & 63;
  const int wv   = tid >> 6;
  const int wm = wv >> 1, wn = wv & 1;
  const size_t rsa = (size_t)jb.lda * 2;      // A row stride bytes
  const size_t rsb = (size_t)jb.ldb * 2;      // B row stride bytes
  const int c0 = wv, c1 = wv + 4;
  const char* Ag0 = (const char*)jb.A + (size_t)(rowB + c0 * 16 + (lane >> 2)) * rsa + (lane & 3) * 16;
  const char* Ag1 = (const char*)jb.A + (size_t)(rowB + c1 * 16 + (lane >> 2)) * rsa + (lane & 3) * 16;
  const char* Bg0 = (const char*)jb.B + (size_t)(colB + c0 * 16 + (lane >> 2)) * rsb + (lane & 3) * 16;
  const char* Bg1 = (const char*)jb.B + (size_t)(colB + c1 * 16 + (lane >> 2)) * rsb + (lane & 3) * 16;
  unsigned short* Al0 = As + c0 * 512;        // wave-uniform LDS base
  unsigned short* Al1 = As + c1 * 512;
  unsigned short* Bl0 = Bs + c0 * 512;
  unsigned short* Bl1 = Bs + c1 * 512;
  f32x4 acc[4][4];
#pragma unroll
  for (int mi = 0; mi < 4; ++mi)
#pragma unroll
    for (int ni = 0; ni < 4; ++ni) acc[mi][ni] = (f32x4){0.f, 0.f, 0.f, 0.f};
  const int KT = K >> 5;
  const int fr = lane & 15, fk = (lane >> 4) * 8;
  for (int kt = 0; kt < KT; ++kt) {
    __syncthreads();                          // prior-iter LDS reads complete
    gload16(Ag0, Al0); gload16(Ag1, Al1);
    gload16(Bg0, Bl0); gload16(Bg1, Bl1);
    Ag0 += 64; Ag1 += 64; Bg0 += 64; Bg1 += 64;
    __syncthreads();                          // drains vmcnt -> LDS tile ready
    bf16x8 af[4], bfv[4];
#pragma unroll
    for (int mi = 0; mi < 4; ++mi)
      af[mi] = *(const bf16x8*)&As[(wm * 64 + mi * 16 + fr) * 32 + fk];
#pragma unroll
    for (int ni = 0; ni < 4; ++ni)
      bfv[ni] = *(const bf16x8*)&Bs[(wn * 64 + ni * 16 + fr) * 32 + fk];
#pragma unroll
    for (int mi = 0; mi < 4; ++mi)
#pragma unroll
      for (int ni = 0; ni < 4; ++ni)
        acc[mi][ni] = __builtin_amdgcn_mfma_f32_16x16x32_bf16(af[mi], bfv[ni], acc[mi][ni], 0, 0, 0);
  }
  // epilogue: C/D layout col=lane&15, row=(lane>>4)*4+j
  const int er = (lane >> 4) * 4, ec = lane & 15;
  if (jb.epi == 0) {
    float* Cf = (float*)jb.C;
#pragma unroll
    for (int mi = 0; mi < 4; ++mi)
#pragma unroll
      for (int ni = 0; ni < 4; ++ni) {
        int row0 = rowB + wm * 64 + mi * 16 + er;
        int col  = colB + wn * 64 + ni * 16 + ec;
#pragma unroll
        for (int j = 0; j < 4; ++j)
          Cf[(size_t)(row0 + j) * ldc + col] = acc[mi][ni][j];
      }
  } else {
    unsigned short* Cb = (unsigned short*)jb.C;
#pragma unroll
    for (int mi = 0; mi < 4; ++mi)
#pragma unroll
      for (int ni = 0; ni < 4; ++ni) {
        int row0 = rowB + wm * 64 + mi * 16 + er;
        int col  = colB + wn * 64 + ni * 16 + ec;
#pragma unroll
        for (int j = 0; j < 4; ++j) {
          float val = acc[mi][ni][j];
          if (jb.epi == 2) val = tanhf(val);
          else if (jb.epi == 3) val = 1.f / (1.f + __expf(-val));
          Cb[(size_t)(row0 + j) * ldc + col] = f2bf(val);
        }
      }
  }
}

// ---------------- split-K partial add: out = p0 + p1 ----------------
__global__ void k_add(const float* __restrict__ p0, const float* __restrict__ p1,
                      float* __restrict__ out) {
  int i = blockIdx.x * 256 + threadIdx.x;
  f32x4 a = *(const f32x4*)(p0 + (size_t)i * 4);
  f32x4 b = *(const f32x4*)(p1 + (size_t)i * 4);
  f32x4 s = a + b;
  *(f32x4*)(out + (size_t)i * 4) = s;
}

// ---------------- post-GEMM elementwise + per-head kk normalize ----------------
__global__ __launch_bounds__(256) void k_post(
    float* __restrict__ Kb, float* __restrict__ Vb, float* __restrict__ Wb,
    float* __restrict__ Ab, float* __restrict__ Bb,
    const float* __restrict__ vf, const float* __restrict__ w0,
    const float* __restrict__ a0, const float* __restrict__ v0,
    const float* __restrict__ kkc, const float* __restrict__ kac) {
  const int wv = threadIdx.x >> 6, lane = threadIdx.x & 63;
  const int gw = blockIdx.x * 4 + wv;         // [0, 16384)
  const int m = gw >> 3, q = gw & 7;
  const int c = q * 256 + lane * 4;
  const size_t idx = (size_t)m * CDIM + c;
  f32x4 kraw = *(const f32x4*)(Kb + idx);
  f32x4 vraw = *(const f32x4*)(Vb + idx);
  f32x4 wlr  = *(const f32x4*)(Wb + idx);
  f32x4 alr  = *(const f32x4*)(Ab + idx);
  f32x4 vlr  = *(const f32x4*)(Bb + idx);
  f32x4 vf4  = *(const f32x4*)(vf + idx);
  f32x4 w04  = *(const f32x4*)(w0 + c);
  f32x4 a04  = *(const f32x4*)(a0 + c);
  f32x4 v04  = *(const f32x4*)(v0 + c);
  f32x4 kkc4 = *(const f32x4*)(kkc + c);
  f32x4 kac4 = *(const f32x4*)(kac + c);
  f32x4 wdec, aa, vv, kk, kn;
#pragma unroll
  for (int j = 0; j < 4; ++j) {
    float z = w04[j] + wlr[j];
    float sg = 1.f / (1.f + __expf(-z));
    wdec[j] = __expf(-0.60653065971f * sg);   // exp(-exp(-softplus(-z)-0.5))
    aa[j] = 1.f / (1.f + __expf(-(a04[j] + alr[j])));
    float vgate = 1.f / (1.f + __expf(-(v04[j] + vlr[j])));
    vv[j] = vraw[j] + (vf4[j] - vraw[j]) * vgate;
    kk[j] = kraw[j] * kkc4[j];
    kn[j] = kraw[j] * (1.f + (aa[j] - 1.f) * kac4[j]);
  }
  float s2 = kk[0] * kk[0] + kk[1] * kk[1] + kk[2] * kk[2] + kk[3] * kk[3];
  s2 = redrow16(s2);                          // full head (16-lane row) sum
  float inv = 1.f / fmaxf(sqrtf(s2), 1e-12f);
  f32x4 nkk = kk * inv;
  *(f32x4*)(Wb + idx) = wdec;
  *(f32x4*)(Vb + idx) = vv;
  *(f32x4*)(Kb + idx) = kn;
  *(f32x4*)(Ab + idx) = -nkk;
  *(f32x4*)(Bb + idx) = nkk * aa;
}

// ---------------- RWKV-7 recurrence (R16-exact, FROZEN @ ~288us) ----------------
__global__ __launch_bounds__(64) void k_scan(
    const float* __restrict__ Rb, const float* __restrict__ Wb,
    const float* __restrict__ Kb, const float* __restrict__ Vb,
    const float* __restrict__ Ab, const float* __restrict__ Bb,
    const float* __restrict__ S0, float* __restrict__ Ob,
    float* __restrict__ Sf) {
  const int bid = blockIdx.x;
  const int bh = bid & 63, vo = bid >> 6;     // vo in 0..15; stride 64 => same XCD
  const int b = bh >> 5, h = bh & 31;
  const int lane = threadIdx.x;
  const int vr = lane & 3;
  const int kq = lane >> 2;
  const int gv = vo * 4 + vr;                 // global v-row in head
  const int kk0 = kq * 4;                     // 4 k per lane
  const bool evr = ((lane >> 4) & 1) == 0;    // even 16-lane row
  const bool lhf = lane < 32;                 // lower 32-lane half
  __shared__ __align__(16) float stg[4][6][64];
  const size_t rowBase = (size_t)b * T_LEN * CDIM;
  const size_t colBase = (size_t)h * 64;
  const float* pR = Rb + rowBase + colBase + lane;
  const float* pW = Wb + rowBase + colBase + lane;
  const float* pK = Kb + rowBase + colBase + lane;
  const float* pV = Vb + rowBase + colBase + lane;
  const float* pA = Ab + rowBase + colBase + lane;
  const float* pB = Bb + rowBase + colBase + lane;
  float* Obp = Ob + rowBase + colBase + vo * 4 + lane;   // valid for lane<4
  f32x4 s0;
  {
    const float* sp = S0 + (((size_t)(b * 32 + h)) * 64 + gv) * 64 + kk0;
    s0 = *(const f32x4*)sp;
  }
  float gA[6], gB[6];
  {   // prologue: stg[0]<-t0, stg[1]<-t1, gA<-t2, gB<-t3
    float h0[6], h1[6];
    h0[0] = pR[0]; h0[1] = pW[0]; h0[2] = pK[0]; h0[3] = pV[0]; h0[4] = pA[0]; h0[5] = pB[0];
    h1[0] = pR[CDIM]; h1[1] = pW[CDIM]; h1[2] = pK[CDIM]; h1[3] = pV[CDIM]; h1[4] = pA[CDIM]; h1[5] = pB[CDIM];
#pragma unroll
    for (int j = 0; j < 6; ++j) { stg[0][j][lane] = h0[j]; stg[1][j][lane] = h1[j]; }
    gA[0] = pR[2 * CDIM]; gA[1] = pW[2 * CDIM]; gA[2] = pK[2 * CDIM];
    gA[3] = pV[2 * CDIM]; gA[4] = pA[2 * CDIM]; gA[5] = pB[2 * CDIM];
    gB[0] = pR[3 * CDIM]; gB[1] = pW[3 * CDIM]; gB[2] = pK[3 * CDIM];
    gB[3] = pV[3 * CDIM]; gB[4] = pA[3 * CDIM]; gB[5] = pB[3 * CDIM];
  }
  // operand register sets: a-set = even steps, b-set = odd steps
  f32x4 aR, aW, aK, aA, aB; float aVV;
  f32x4 bR, bW, bK, bA, bB; float bVV;
  // init a-set <- slot 0 (t0), written in prologue (in-order DS)
  aR = *(const f32x4*)&stg[0][0][kk0];
  aW = *(const f32x4*)&stg[0][1][kk0];
  aK = *(const f32x4*)&stg[0][2][kk0];
  aA = *(const f32x4*)&stg[0][4][kk0];
  aB = *(const f32x4*)&stg[0][5][kk0];
  aVV = stg[0][3][gv];
  float pox = 0.f;                            // deferred o partial (prev step)
#define SCAN_STEP(T, G, SR,SW,SK,SA,SB,SVV, NR,NW,NK,NA,NB,NVV, FIRST) do {    \
    f32x4 _sv = SA * s0;                                                       \
    float _sa = _sv[0] + _sv[1] + _sv[2] + _sv[3];                             \
    { const int _np = ((T) + 1) & 3;        /* prefetch next-step operands */  \
      NR = *(const f32x4*)&stg[_np][0][kk0];                                   \
      NW = *(const f32x4*)&stg[_np][1][kk0];                                   \
      NK = *(const f32x4*)&stg[_np][2][kk0];                                   \
      NA = *(const f32x4*)&stg[_np][4][kk0];                                   \
      NB = *(const f32x4*)&stg[_np][5][kk0];                                   \
      NVV = stg[_np][3][gv]; }                                                 \
    float _po = pox;                                                           \
    _sa = redrot<0x124>(_sa); _po = redrot<0x124>(_po);                        \
    _sa = redrot<0x128>(_sa); _po = redrot<0x128>(_po);                        \
    _sa = red16(_sa, evr);    _po = red16(_po, evr);                           \
    _sa = red32(_sa, lhf);    _po = red32(_po, lhf);                           \
    if (!(FIRST) && lane < 4) Obp[(size_t)((T) - 1) * CDIM] = _po;             \
    { const int _ws = ((T) + 2) & 3;                                           \
      stg[_ws][0][lane] = G[0]; stg[_ws][1][lane] = G[1];                      \
      stg[_ws][2][lane] = G[2]; stg[_ws][3][lane] = G[3];                      \
      stg[_ws][4][lane] = G[4]; stg[_ws][5][lane] = G[5];                      \
      const size_t _to = (size_t)(((T) + 4 < T_LEN) ? (T) + 4 : T_LEN - 1) * CDIM; \
      G[0] = pR[_to]; G[1] = pW[_to]; G[2] = pK[_to];                          \
      G[3] = pV[_to]; G[4] = pA[_to]; G[5] = pB[_to]; }                        \
    s0 = s0 * SW + _sa * SB + SVV * SK;                                        \
    f32x4 _ov = s0 * SR;                                                       \
    pox = _ov[0] + _ov[1] + _ov[2] + _ov[3];                                   \
  } while (0)
#define SCAN_STEP_I(...) SCAN_STEP(__VA_ARGS__)
#define ASET aR,aW,aK,aA,aB,aVV
#define BSET bR,bW,bK,bA,bB,bVV
  SCAN_STEP_I(0, gA, ASET, BSET, true);
  SCAN_STEP_I(1, gB, BSET, ASET, false);
  for (int t = 2; t < T_LEN; t += 2) {
    SCAN_STEP_I(t, gA, ASET, BSET, false);
    SCAN_STEP_I(t + 1, gB, BSET, ASET, false);
  }
#undef SCAN_STEP
#undef SCAN_STEP_I
#undef ASET
#undef BSET
  {   // flush o_{T_LEN-1}
    float _po = pox;
    _po = redrot<0x124>(_po);
    _po = redrot<0x128>(_po);
    _po = red16(_po, evr);
    _po = red32(_po, lhf);
    if (lane < 4) Obp[(size_t)(T_LEN - 1) * CDIM] = _po;
  }
  float* sfp = Sf + (((size_t)(b * 32 + h)) * 64 + gv) * 64 + kk0;
  *(f32x4*)sfp = s0;
}

// ---------------- GroupNorm + bonus + gate -> bf16 A for out-proj ----------------
__global__ __launch_bounds__(256) void k_gn(
    const float* __restrict__ Ob, const float* __restrict__ Rb,
    const float* __restrict__ Kb, const float* __restrict__ Vb,
    const float* __restrict__ Gb, const float* __restrict__ rk,
    const float* __restrict__ gw, const float* __restrict__ gb2,
    unsigned short* __restrict__ Aout) {
  const int wv = threadIdx.x >> 6, lane = threadIdx.x & 63;
  const int gwv = blockIdx.x * 4 + wv;        // [0, 16384)
  const int m = gwv >> 3, q = gwv & 7;
  const int c = q * 256 + lane * 4;
  const size_t idx = (size_t)m * CDIM + c;
  f32x4 o  = *(const f32x4*)(Ob + idx);
  f32x4 r  = *(const f32x4*)(Rb + idx);
  f32x4 k  = *(const f32x4*)(Kb + idx);
  f32x4 v  = *(const f32x4*)(Vb + idx);
  f32x4 g  = *(const f32x4*)(Gb + idx);
  f32x4 rk4 = *(const f32x4*)(rk + c);
  f32x4 gw4 = *(const f32x4*)(gw + c);
  f32x4 gb4 = *(const f32x4*)(gb2 + c);
  float t1 = o[0] + o[1] + o[2] + o[3];
  float t2 = o[0]*o[0] + o[1]*o[1] + o[2]*o[2] + o[3]*o[3];
  f32x4 rkv = r * k * rk4;
  float t3 = rkv[0] + rkv[1] + rkv[2] + rkv[3];
  t1 = redrow16(t1);
  t2 = redrow16(t2);
  t3 = redrow16(t3);
  float mean = t1 * (1.f / 64.f);
  float var = t2 * (1.f / 64.f) - mean * mean;
  float rstd = rsqrtf(var + 6.4e-4f);         // eps = 1e-5 * 64
  f32x4 og = (o - mean) * rstd * gw4 + gb4 + t3 * v;
  st_bf4(Aout + idx, og * g);
}

// ---------------- launch ----------------
extern "C" void kernel_launch(void* const* d_in, const int* in_sizes, int n_in,
                              void* d_out, int out_size, void* d_ws, size_t ws_size,
                              hipStream_t stream) {
  (void)in_sizes; (void)n_in; (void)out_size; (void)ws_size;
  const float* x      = (const float*)d_in[0];
  const float* vfirst = (const float*)d_in[1];
  const float* shift  = (const float*)d_in[2];
  const float* wkv0   = (const float*)d_in[3];
  const float* xr_c   = (const float*)d_in[4];
  const float* xw_c   = (const float*)d_in[5];
  const float* xk_c   = (const float*)d_in[6];
  const float* xv_c   = (const float*)d_in[7];
  const float* xa_c   = (const float*)d_in[8];
  const float* xg_c   = (const float*)d_in[9];
  const float* w0     = (const float*)d_in[10];
  const float* w1     = (const float*)d_in[11];
  const float* w2     = (const float*)d_in[12];
  const float* a0     = (const float*)d_in[13];
  const float* a1     = (const float*)d_in[14];
  const float* a2     = (const float*)d_in[15];
  const float* v0     = (const float*)d_in[16];
  const float* v1     = (const float*)d_in[17];
  const float* v2     = (const float*)d_in[18];
  const float* g1     = (const float*)d_in[19];
  const float* g2     = (const float*)d_in[20];
  const float* k_k    = (const float*)d_in[21];
  const float* k_a    = (const float*)d_in[22];
  const float* r_k    = (const float*)d_in[23];
  const float* W_r    = (const float*)d_in[24];
  const float* W_k    = (const float*)d_in[25];
  const float* W_v    = (const float*)d_in[26];
  const float* W_o    = (const float*)d_in[27];
  const float* gn_w   = (const float*)d_in[28];
  const float* gn_b   = (const float*)d_in[29];
  char* ws = (char*)d_ws;
  auto BF = [&](size_t o) { return (unsigned short*)(ws + o); };
  auto FP = [&](size_t o) { return (float*)(ws + o); };

  // weights -> bf16 (one launch; 1048576 float4-chunks PER matrix)
  { Conv4 cb{W_r, W_k, W_v, W_o, BF(oWr), BF(oWk), BF(oWv), BF(oWo)};
    k_conv4<<<dim3(4096, 4), 256, 0, stream>>>(cb, 1048576); }
  // small weights -> transposed, zero-padded bf16 (8 jobs, one launch)
  { TpJobs jt{};
    jt.src[0] = w1; jt.dst[0] = BF(oW1T); jt.sR[0] = 2048; jt.sC[0] = 96;   jt.dR[0] = 128;  jt.dC[0] = 2048;
    jt.src[1] = a1; jt.dst[1] = BF(oA1T); jt.sR[1] = 2048; jt.sC[1] = 96;   jt.dR[1] = 128;  jt.dC[1] = 2048;
    jt.src[2] = v1; jt.dst[2] = BF(oV1T); jt.sR[2] = 2048; jt.sC[2] = 64;   jt.dR[2] = 128;  jt.dC[2] = 2048;
    jt.src[3] = g1; jt.dst[3] = BF(oG1T); jt.sR[3] = 2048; jt.sC[3] = 256;  jt.dR[3] = 256;  jt.dC[3] = 2048;
    jt.src[4] = w2; jt.dst[4] = BF(oW2T); jt.sR[4] = 96;   jt.sC[4] = 2048; jt.dR[4] = 2048; jt.dC[4] = 128;
    jt.src[5] = a2; jt.dst[5] = BF(oA2T); jt.sR[5] = 96;   jt.sC[5] = 2048; jt.dR[5] = 2048; jt.dC[5] = 128;
    jt.src[6] = v2; jt.dst[6] = BF(oV2T); jt.sR[6] = 64;   jt.sC[6] = 2048; jt.dR[6] = 2048; jt.dC[6] = 128;
    jt.src[7] = g2; jt.dst[7] = BF(oG2T); jt.sR[7] = 256;  jt.sC[7] = 2048; jt.dR[7] = 2048; jt.dC[7] = 256;
    k_tp8<<<dim3(2048, 8), 256, 0, stream>>>(jt); }
  // token shift + mixes (8 floats/thread)
  k_mix<<<2048, 256, 0, stream>>>(x, shift, xr_c, xw_c, xk_c, xv_c, xa_c, xg_c,
                                  BF(oXr), BF(oXw), BF(oXk), BF(oXv), BF(oXa), BF(oXg));
  // QKV projections + ALL stage-1 low-rank GEMMs in ONE launch (z=7)
  { GemmBatch gb{};
    gb.j[0] = {BF(oXr), BF(oWr),  FP(oR),  0, 2048, 2048, 2048, 2048, 2048};
    gb.j[1] = {BF(oXk), BF(oWk),  FP(oK),  0, 2048, 2048, 2048, 2048, 2048};
    gb.j[2] = {BF(oXv), BF(oWv),  FP(oV),  0, 2048, 2048, 2048, 2048, 2048};
    gb.j[3] = {BF(oXw), BF(oW1T), BF(oHw), 2, 128, 128, 2048, 2048, 2048};   // tanh
    gb.j[4] = {BF(oXa), BF(oA1T), BF(oHa), 1, 128, 128, 2048, 2048, 2048};
    gb.j[5] = {BF(oXv), BF(oV1T), BF(oHv), 1, 128, 128, 2048, 2048, 2048};
    gb.j[6] = {BF(oXg), BF(oG1T), BF(oHg), 3, 256, 256, 2048, 2048, 2048};   // sigmoid
    k_gemm_nt<<<dim3(16, 16, 7), 256, 0, stream>>>(gb); }
  // stage-2 low-rank (K=128) + gate stage-2 (K=256) in ONE launch (z=4)
  { GemmBatch gb{};
    gb.j[0] = {BF(oHw), BF(oW2T), FP(oWW), 0, 2048, 2048, 128, 128, 128};
    gb.j[1] = {BF(oHa), BF(oA2T), FP(oAA), 0, 2048, 2048, 128, 128, 128};
    gb.j[2] = {BF(oHv), BF(oV2T), FP(oBB), 0, 2048, 2048, 128, 128, 128};
    gb.j[3] = {BF(oHg), BF(oG2T), FP(oG),  0, 2048, 2048, 256, 256, 256};
    k_gemm_nt<<<dim3(16, 16, 4), 256, 0, stream>>>(gb); }
  // elementwise post (decay, a, v-blend, kk-normalize, k update) -- vectorized
  k_post<<<4096, 256, 0, stream>>>(FP(oK), FP(oV), FP(oWW), FP(oAA), FP(oBB),
                                   vfirst, w0, a0, v0, k_k, k_a);
  // recurrence: 1024 single-wave blocks (4 v-rows each)
  k_scan<<<1024, 64, 0, stream>>>(FP(oR), FP(oWW), FP(oK), FP(oV), FP(oAA), FP(oBB),
                                  wkv0, FP(oO), (float*)d_out + MC);
  // groupnorm + bonus + gate -- vectorized
  k_gn<<<4096, 256, 0, stream>>>(FP(oO), FP(oR), FP(oK), FP(oV), FP(oG),
                                 r_k, gn_w, gn_b, BF(oAout));
  // output projection, split-K=2 (z=2, 512 blocks co-resident); partials into
  // dead scan buffers oWW/oAA, then summed into d_out.
  { GemmBatch gb{};
    gb.j[0] = {BF(oAout),        BF(oWo),        FP(oWW), 0, 2048, 2048, 1024, 2048, 2048};
    gb.j[1] = {BF(oAout) + 1024, BF(oWo) + 1024, FP(oAA), 0, 2048, 2048, 1024, 2048, 2048};
    k_gemm_nt<<<dim3(16, 16, 2), 256, 0, stream>>>(gb); }
  k_add<<<4096, 256, 0, stream>>>(FP(oWW), FP(oAA), (float*)d_out);
}